// Round 13
// baseline (923.681 us; speedup 1.0000x reference)
//
#include <hip/hip_runtime.h>

#define T_STEPS 10
#define NN 10000
#define EE 320000
#define CC 128
#define NC (NN*CC)
#define BHIST 32
#define EPB (EE/BHIST)   // 10000 edges per hist block
#define NCHK 40          // ceil(NN/256) scan chunks
#define PRS 8            // place row slices
#define PES 4            // place edge slices
#define PROWS (NN/PRS)   // 1250 rows per place block
#define PEDG (EE/PES)    // 80000 edges per place slice

typedef unsigned short u16;
typedef unsigned int u32;
typedef __attribute__((ext_vector_type(8))) short bf16x8;
typedef __attribute__((ext_vector_type(4))) float f32x4;

__device__ __forceinline__ float sigmoidf_(float x){ return 1.f/(1.f+__expf(-x)); }
__device__ __forceinline__ float tanhf_(float x){
  x = fminf(15.f, fmaxf(-15.f, x));
  float e = __expf(2.f*x);
  return (e-1.f)/(e+1.f);
}
__device__ __forceinline__ u16 f2bf(float f){
  u32 u = __float_as_uint(f);
  u32 r = u + 0x7fffu + ((u>>16)&1u);
  return (u16)(r>>16);
}
__device__ __forceinline__ float bf2f(u16 s){
  return __uint_as_float(((u32)s)<<16);
}
__device__ __forceinline__ float blo(u32 u){ return __uint_as_float(u<<16); }
__device__ __forceinline__ float bhi(u32 u){ return __uint_as_float(u & 0xffff0000u); }
__device__ __forceinline__ void gload16(const void* g, void* l){
  __builtin_amdgcn_global_load_lds(
    (const __attribute__((address_space(1))) void*)g,
    (__attribute__((address_space(3))) void*)l, 16, 0, 0);
}

// ---------------- prep: transposed bf16 effective weights + biases + h0 -----
__global__ __launch_bounds__(256) void prep_kernel(
    const float* __restrict__ Wxz, const float* __restrict__ Whz,
    const float* __restrict__ Wxr, const float* __restrict__ Whr,
    const float* __restrict__ Wxh, const float* __restrict__ Whh,
    const float* __restrict__ bxz, const float* __restrict__ bhz,
    const float* __restrict__ bxr, const float* __restrict__ bhr,
    const float* __restrict__ bxh, const float* __restrict__ bhh,
    const float* __restrict__ Wp,
    u16* __restrict__ WbigT, u16* __restrict__ WrT, u16* __restrict__ WpT,
    float* __restrict__ bz, float* __restrict__ br, float* __restrict__ bht,
    u16* __restrict__ h)
{
  int idx = blockIdx.x*256 + threadIdx.x;
  if (idx < NC) h[idx] = 0;
  if (idx < 384*768) {
    int c = idx / 768, k = idx - c*768;
    int gate = c >> 7, cc = c & 127;
    int hside = (k >= 384);
    int kk = hside ? k - 384 : k;
    int blk = kk >> 7, row = kk & 127;
    const float* W = nullptr;
    if (!hside) W = (gate==0) ? Wxz : (gate==1) ? Wxr : Wxh;
    else if (gate==0) W = Whz; else if (gate==1) W = Whr;
    float v = 0.f;
    if (W) {
      int base = row*CC + cc;
      float w0 = W[base], w1 = W[CC*CC + base], w2 = W[2*CC*CC + base];
      v = (blk==0) ? (w0 - w2) : (blk==1) ? w1 : (2.f*w2);
    }
    WbigT[idx] = f2bf(v);
  }
  if (idx < 128*384) {
    int c = idx / 384, k = idx - c*384;
    int blk = k >> 7, row = k & 127;
    int base = row*CC + c;
    float w0 = Whh[base], w1 = Whh[CC*CC+base], w2 = Whh[2*CC*CC+base];
    WrT[idx] = f2bf((blk==0) ? (w0-w2) : (blk==1) ? w1 : (2.f*w2));
  }
  if (idx < 64*128) {
    int c = idx >> 7, k = idx & 127;
    WpT[idx] = f2bf(Wp[k*64 + c]);
  }
  if (idx < CC) {
    bz[idx]  = bxz[idx] + bhz[idx];
    br[idx]  = bxr[idx] + bhr[idx];
    bht[idx] = bxh[idx] + bhh[idx];
  }
}

// fp32 -> bf16, 4 elems/thread; n4 = number of float4 chunks
__global__ __launch_bounds__(256) void xconv_kernel(const float* __restrict__ x, u16* __restrict__ xb, int n4){
  int i = blockIdx.x*256 + threadIdx.x;
  if (i >= n4) return;
  long long o = (long long)i*4;
  float4 v = *(const float4*)(x + o);
  u32 u0 = (u32)f2bf(v.x) | ((u32)f2bf(v.y)<<16);
  u32 u1 = (u32)f2bf(v.z) | ((u32)f2bf(v.w)<<16);
  uint2 r; r.x=u0; r.y=u1;
  *(uint2*)(xb + o) = r;
}

// ---------------- graph build: packed LDS histograms, zero global atomics --
__global__ __launch_bounds__(512) void hist_kernel(const int* __restrict__ edges,
                                                   u32* __restrict__ histP){
  __shared__ u32 hist[NN];   // 40 KB
  int t = blockIdx.y, b = blockIdx.x, tid = threadIdx.x;
  for (int i = tid; i < NN; i += 512) hist[i] = 0;
  __syncthreads();
  const int* src = edges + (size_t)t*2*EE;
  const int* dst = src + EE;
  int e1 = b*EPB + EPB;
  #pragma unroll 4
  for (int e = b*EPB + tid; e < e1; e += 512){
    int s = src[e], d = dst[e];
    if (s != d){
      atomicAdd(&hist[s], 1u);         // ds_add, LDS-local
      atomicAdd(&hist[d], 1u << 16);
    }
  }
  __syncthreads();
  u32* hp = histP + ((size_t)t*BHIST + b)*NN;
  for (int i = tid; i < NN; i += 512) hp[i] = hist[i];
}

// reduce+chunk-scan: per (t,chunk of 256 nodes): deg->dinv; per-block cnt
// exclusive prefix into partial high16; chunk-local exclusive scan into
// rowptr; chunk totals out.
__global__ __launch_bounds__(256) void reduce_scan_kernel(u32* __restrict__ histP,
                                                          int* __restrict__ rowptr_all,
                                                          int* __restrict__ chunk_tot,
                                                          float* __restrict__ dinv_all){
  int t = blockIdx.y, ch = blockIdx.x, tid = threadIdx.x;
  int d = ch*256 + tid;
  u32 run=0, degs=0;
  if (d < NN){
    size_t base = (size_t)t*BHIST*NN + d;
    #pragma unroll
    for (int b=0;b<BHIST;++b){
      size_t ix = base + (size_t)b*NN;
      u32 v = histP[ix];
      histP[ix] = (v & 0xffffu) | (run<<16);
      run += v>>16;
      degs += v & 0xffffu;
    }
    dinv_all[t*NN+d] = degs>0 ? rsqrtf((float)degs) : 0.f;
  }
  int lane = tid&63, wv = tid>>6;
  int s = (int)run;
  #pragma unroll
  for (int off=1; off<64; off<<=1){
    int u = __shfl_up(s, off, 64);
    if (lane>=off) s += u;
  }
  __shared__ int wsum[4];
  if (lane==63) wsum[wv] = s;
  __syncthreads();
  int add = 0;
  #pragma unroll
  for (int w=0; w<3; ++w) if (w < wv) add += wsum[w];
  int incl = s + add;
  if (d < NN) rowptr_all[(size_t)t*(NN+1)+d] = incl - (int)run;
  if (tid==255) chunk_tot[t*NCHK + ch] = incl;
}

// scan of NCHK chunk totals per t (one wave)
__global__ __launch_bounds__(64) void scanb_kernel(const int* __restrict__ chunk_tot,
                                                   int* __restrict__ chunk_base,
                                                   int* __restrict__ rowptr_all){
  int t = blockIdx.x; int lane = threadIdx.x;
  int v = (lane < NCHK) ? chunk_tot[t*NCHK+lane] : 0;
  int s = v;
  #pragma unroll
  for (int off=1; off<64; off<<=1){
    int u = __shfl_up(s, off, 64);
    if (lane>=off) s += u;
  }
  if (lane < NCHK) chunk_base[t*NCHK+lane] = s - v;
  if (lane == NCHK-1) rowptr_all[(size_t)t*(NN+1)+NN] = s;
}

__global__ __launch_bounds__(256) void scanc_kernel(int* __restrict__ rowptr_all,
                                                    const int* __restrict__ chunk_base){
  int t = blockIdx.y, ch = blockIdx.x;
  int d = ch*256 + threadIdx.x;
  if (d < NN) rowptr_all[(size_t)t*(NN+1)+d] += chunk_base[t*NCHK+ch];
}

// place: hybrid counting-sort scatter. Block (rs,es,t) scans edge-slice es
// (80K edges) and ranks only dst in its 1250-row slice; LDS counters seeded
// with rowptr + the es-slice exclusive base (= histP high16 at block es*8,
// the running prefix reduce_scan wrote). Writers per colA row-segment drop
// 32 -> 4 (PES), killing most cross-XCD partial-line write amplification.
__global__ __launch_bounds__(512) void place_kernel(const int* __restrict__ edges,
                                                    const int* __restrict__ rowptr_all,
                                                    const u32* __restrict__ histP,
                                                    u16* __restrict__ colA_all){
  __shared__ int slot[PROWS];     // 5 KB
  int t = blockIdx.y, b = blockIdx.x, tid = threadIdx.x;
  int rs = b >> 2, es = b & 3;
  int lo = rs*PROWS, hi = lo + PROWS;
  const int* rowptr = rowptr_all + (size_t)t*(NN+1);
  const u32* hp = histP + ((size_t)t*BHIST + es*8)*NN;
  for (int i = tid; i < PROWS; i += 512)
    slot[i] = rowptr[lo+i] + (int)(hp[lo+i] >> 16);
  __syncthreads();
  const int* src = edges + (size_t)t*2*EE;
  const int* dst = src + EE;
  u16* colA = colA_all + (size_t)t*EE;
  int e1 = es*PEDG + PEDG;
  #pragma unroll 4
  for (int e = es*PEDG + tid; e < e1; e += 512){
    int d = dst[e];
    if (d >= lo && d < hi){
      int s = src[e];
      if (s != d){
        int pos = atomicAdd(&slot[d-lo], 1);   // LDS atomic, returns rank
        colA[pos] = (u16)s;
      }
    }
  }
}

// ---------------- CSR SpMM core: quad-edge, one wave per row ---------------
// 4 lane-groups of 16; group q processes edges k0+q, k0+q+4, ...; each group
// covers all 128 channels via uint4 (16B x 16 lanes = 256B row) -> 4 edges
// in flight, trips/4. Merge via shfl_xor(16)+shfl_xor(32); group 0 writes.
// -dinv[row] applied once at the end.
__device__ __forceinline__ void spmm_row4(const int* __restrict__ rowptr, const u16* __restrict__ colA,
                                          const float* __restrict__ dinv,
                                          const u16* __restrict__ in, u16* __restrict__ out,
                                          int wb, int wave, int lane){
  int row = wb*4 + wave;
  int k0 = rowptr[row], k1 = rowptr[row+1];
  int q = lane >> 4, cl = lane & 15;      // channels 8cl..8cl+7
  float a0=0.f,a1=0.f,a2=0.f,a3=0.f,a4=0.f,a5=0.f,a6=0.f,a7=0.f;
  #pragma unroll 2
  for (int k = k0 + q; k < k1; k += 4){
    int s = colA[k];
    float w = dinv[s];
    uint4 u = *(const uint4*)(in + (size_t)s*CC + cl*8);
    a0 = fmaf(w, blo(u.x), a0);  a1 = fmaf(w, bhi(u.x), a1);
    a2 = fmaf(w, blo(u.y), a2);  a3 = fmaf(w, bhi(u.y), a3);
    a4 = fmaf(w, blo(u.z), a4);  a5 = fmaf(w, bhi(u.z), a5);
    a6 = fmaf(w, blo(u.w), a6);  a7 = fmaf(w, bhi(u.w), a7);
  }
  a0 += __shfl_xor(a0,16); a1 += __shfl_xor(a1,16);
  a2 += __shfl_xor(a2,16); a3 += __shfl_xor(a3,16);
  a4 += __shfl_xor(a4,16); a5 += __shfl_xor(a5,16);
  a6 += __shfl_xor(a6,16); a7 += __shfl_xor(a7,16);
  a0 += __shfl_xor(a0,32); a1 += __shfl_xor(a1,32);
  a2 += __shfl_xor(a2,32); a3 += __shfl_xor(a3,32);
  a4 += __shfl_xor(a4,32); a5 += __shfl_xor(a5,32);
  a6 += __shfl_xor(a6,32); a7 += __shfl_xor(a7,32);
  if (q == 0){
    float wrow = -dinv[row];
    uint4 r;
    r.x = (u32)f2bf(wrow*a0) | ((u32)f2bf(wrow*a1)<<16);
    r.y = (u32)f2bf(wrow*a2) | ((u32)f2bf(wrow*a3)<<16);
    r.z = (u32)f2bf(wrow*a4) | ((u32)f2bf(wrow*a5)<<16);
    r.w = (u32)f2bf(wrow*a6) | ((u32)f2bf(wrow*a7)<<16);
    *(uint4*)(out + (size_t)row*CC + cl*8) = r;
  }
}

// single-input (hr path)
__global__ __launch_bounds__(256) void spmm_kernel(const int* __restrict__ rowptr, const u16* __restrict__ colA,
                                                   const float* __restrict__ dinv,
                                                   const u16* __restrict__ in, u16* __restrict__ out){
  int wave = threadIdx.x >> 6, lane = threadIdx.x & 63;
  int wb = blockIdx.x;
  if (wb >= NN/4) return;
  spmm_row4(rowptr, colA, dinv, in, out, wb, wave, lane);
}

// dual-input, XCD-pinned: xcd 0-3 -> input0, 4-7 -> input1; per-XCD L2
// working set = one 2.5MB matrix.
__global__ __launch_bounds__(256) void spmm2_kernel(const int* __restrict__ rowptr, const u16* __restrict__ colA,
                                                    const float* __restrict__ dinv,
                                                    const u16* __restrict__ in0, u16* __restrict__ out0,
                                                    const u16* __restrict__ in1, u16* __restrict__ out1){
  int wave = threadIdx.x >> 6, lane = threadIdx.x & 63;
  int bid = blockIdx.x;
  int xcd = bid & 7;
  int inp = xcd >> 2;
  int wb  = (bid >> 3)*4 + (xcd & 3);
  if (wb >= NN/4) return;
  spmm_row4(rowptr, colA, dinv, inp?in1:in0, inp?out1:out0, wb, wave, lane);
}

// ---------------- bf16 MFMA GEMM over segmented K, BK=128 ------------------
// BM=BN=64, BK=128 (one full segment per staging round -> half the barrier
// rounds vs BK=64; grid unchanged: keep block count high, r9 lesson).
// 4 waves/block, each wave a 32x32 quadrant (2x2 frags of 16x16x32).
// LDS [64 rows][16 x 16B chunks] per matrix, XOR swizzle chunk^=(row&15),
// staged by global_load_lds with pre-swizzled SOURCE (both-sides rule #21).
// SWZN>0: 1D grid 8*20*SWZN, XCD bid&7 owns a contiguous 20-m-tile stripe.
// EPI 1 + n0>=256 (h~ cols): h-side B rows are structurally zero ->
// run only the x-side segments (K-skip).
template<int NSEG, int KDIM, int EPI, int SWZN>
__global__ __launch_bounds__(256) void mgemm_kernel(
    const u16* __restrict__ A0, const u16* __restrict__ A1, const u16* __restrict__ A2,
    const u16* __restrict__ A3, const u16* __restrict__ A4, const u16* __restrict__ A5,
    const u16* __restrict__ Bt,
    const float* __restrict__ bias0, const float* __restrict__ bias1,
    const u16* __restrict__ hbuf,
    float* __restrict__ zbuf, float* __restrict__ chx,
    u16* __restrict__ hr_out, u16* __restrict__ h_out,
    float* __restrict__ out_f)
{
  __shared__ __align__(16) u16 As[64*128];
  __shared__ __align__(16) u16 Bs[64*128];
  const u16* segs[6] = {A0,A1,A2,A3,A4,A5};
  int tid = threadIdx.x, lane = tid & 63, wvi = tid >> 6;
  int m0, n0;
  if (SWZN > 0){
    int bid = blockIdx.x;
    int j = bid >> 3;
    int mt = (bid & 7)*20 + (j % 20);
    if (mt >= 157) return;
    m0 = mt*64; n0 = (j/20)*64;
  } else {
    m0 = blockIdx.x*64; n0 = blockIdx.y*64;
  }
  int wr = wvi >> 1, wc = wvi & 1;

  f32x4 acc[2][2] = {};

  // staging: 1024 chunks of 16B per matrix; thread handles chunks
  // c = i*256 + c_lo (i=0..3): row = c>>4, slot = c&15, src slot = slot^(row&15)
  int c_lo = wvi*64 + lane;
  // fragment read offsets (bytes); same XOR on the 16B-chunk index
  int rl = lane & 15, rg = lane >> 4;
  int offA[2][4], offB[2][4];
  #pragma unroll
  for (int mf=0; mf<2; ++mf)
    #pragma unroll
    for (int ks=0; ks<4; ++ks){
      offA[mf][ks] = (wr*32 + mf*16 + rl)*256 + ((((ks<<2)+rg) ^ rl)<<4);
      offB[mf][ks] = (wc*32 + mf*16 + rl)*256 + ((((ks<<2)+rg) ^ rl)<<4);
    }

  const int ktend = (EPI==1 && n0 >= 256) ? (NSEG/2) : NSEG;  // K-skip h~ cols
  for (int kt=0; kt<ktend; ++kt){
    const u16* __restrict__ Aseg = segs[kt];
    __syncthreads();   // previous iteration's LDS reads done before overwrite
    #pragma unroll
    for (int i=0;i<4;++i){
      int c = i*256 + c_lo;
      int row = c >> 4, slot = c & 15;
      int scw = slot ^ (row & 15);
      int grow = m0 + row; if (grow > NN-1) grow = NN-1;
      gload16(Aseg + (size_t)grow*CC + scw*8,
              (u16*)As + ((size_t)i*256 + wvi*64)*8);
      gload16(Bt + (size_t)(n0 + row)*KDIM + kt*128 + scw*8,
              (u16*)Bs + ((size_t)i*256 + wvi*64)*8);
    }
    __syncthreads();   // compiler drains vmcnt before s_barrier -> data ready
    #pragma unroll
    for (int ks=0; ks<4; ++ks){
      bf16x8 a0 = *(const bf16x8*)((const char*)As + offA[0][ks]);
      bf16x8 a1 = *(const bf16x8*)((const char*)As + offA[1][ks]);
      bf16x8 b0 = *(const bf16x8*)((const char*)Bs + offB[0][ks]);
      bf16x8 b1 = *(const bf16x8*)((const char*)Bs + offB[1][ks]);
      acc[0][0] = __builtin_amdgcn_mfma_f32_16x16x32_bf16(a0, b0, acc[0][0], 0,0,0);
      acc[0][1] = __builtin_amdgcn_mfma_f32_16x16x32_bf16(a0, b1, acc[0][1], 0,0,0);
      acc[1][0] = __builtin_amdgcn_mfma_f32_16x16x32_bf16(a1, b0, acc[1][0], 0,0,0);
      acc[1][1] = __builtin_amdgcn_mfma_f32_16x16x32_bf16(a1, b1, acc[1][1], 0,0,0);
    }
  }

  // epilogue: C/D layout col=lane&15, row=(lane>>4)*4+reg  [guide m89]
  #pragma unroll
  for (int mf=0; mf<2; ++mf){
    #pragma unroll
    for (int nf=0; nf<2; ++nf){
      #pragma unroll
      for (int r=0; r<4; ++r){
        int grow = m0 + wr*32 + mf*16 + rg*4 + r;
        if (grow >= NN) continue;
        int gcol = n0 + wc*32 + nf*16 + rl;
        float v = acc[mf][nf][r];
        if (EPI==0){
          out_f[(size_t)grow*64 + gcol] = v + bias0[gcol];
        } else if (EPI==1){
          int gate = gcol >> 7, c = gcol & 127;
          size_t idx = (size_t)grow*CC + c;
          if (gate==0)      zbuf[idx] = sigmoidf_(v + bias0[c]);
          else if (gate==1){
            float rr = sigmoidf_(v + bias1[c]);
            hr_out[idx] = f2bf(rr * bf2f(hbuf[idx]));
          } else            chx[idx] = v;
        } else {
          size_t idx = (size_t)grow*CC + gcol;
          float pre = v + chx[idx] + bias0[gcol];
          float ht = tanhf_(pre);
          float zz = zbuf[idx];
          float hv = bf2f(hbuf[idx]);
          h_out[idx] = f2bf(fmaf(zz, hv - ht, ht));
        }
      }
    }
  }
}

extern "C" void kernel_launch(void* const* d_in, const int* in_sizes, int n_in,
                              void* d_out, int out_size, void* d_ws, size_t ws_size,
                              hipStream_t stream)
{
  (void)in_sizes; (void)n_in; (void)out_size; (void)ws_size;
  const float* feat = (const float*)d_in[0];
  const int*   edges = (const int*)d_in[1];
  const float* Wxz=(const float*)d_in[2];  const float* bxz=(const float*)d_in[3];
  const float* Whz=(const float*)d_in[4];  const float* bhz=(const float*)d_in[5];
  const float* Wxr=(const float*)d_in[6];  const float* bxr=(const float*)d_in[7];
  const float* Whr=(const float*)d_in[8];  const float* bhr=(const float*)d_in[9];
  const float* Wxh=(const float*)d_in[10]; const float* bxh=(const float*)d_in[11];
  const float* Whh=(const float*)d_in[12]; const float* bhh=(const float*)d_in[13];
  const float* Wp =(const float*)d_in[14]; const float* bp =(const float*)d_in[15];
  float* out = (float*)d_out;

  char* p = (char*)d_ws;
  auto alloc = [&](size_t bytes)->char* {
    char* r = p; p += (bytes + 255) & ~(size_t)255; return r;
  };
  u16* xb   = (u16*)alloc((size_t)T_STEPS*NC*2);
  u16* h    = (u16*)alloc((size_t)NC*2);
  u16* a1x  = (u16*)alloc((size_t)NC*2);
  u16* a2x  = (u16*)alloc((size_t)NC*2);
  u16* a1h  = (u16*)alloc((size_t)NC*2);
  u16* a2h  = (u16*)alloc((size_t)NC*2);
  u16* hr   = (u16*)alloc((size_t)NC*2);
  float* zbuf = (float*)alloc((size_t)NC*4);
  float* chx  = (float*)alloc((size_t)NC*4);
  u16* WbigT = (u16*)alloc(384*768*2);
  u16* WrT   = (u16*)alloc(128*384*2);
  u16* WpT   = (u16*)alloc(64*128*2);
  float* bz  = (float*)alloc(CC*4);
  float* br  = (float*)alloc(CC*4);
  float* bht = (float*)alloc(CC*4);
  float* dinv_all = (float*)alloc((size_t)T_STEPS*NN*4);
  int* rowptr_all = (int*)alloc((size_t)T_STEPS*(NN+1)*4);
  u16* colA_all   = (u16*)alloc((size_t)T_STEPS*EE*2);
  int* chunk_tot  = (int*)alloc((size_t)T_STEPS*NCHK*4);
  int* chunk_base = (int*)alloc((size_t)T_STEPS*NCHK*4);
  // packed hist partials (12.8MB) alias hr+zbuf+chx (contiguous exact-256B
  // sizes; dead before the recurrence loop first writes them)
  u32* histP = (u32*)hr;

  prep_kernel<<<NC/256, 256, 0, stream>>>(Wxz,Whz,Wxr,Whr,Wxh,Whh,
                                          bxz,bhz,bxr,bhr,bxh,bhh, Wp,
                                          WbigT, WrT, WpT, bz, br, bht, h);
  xconv_kernel<<<(T_STEPS*NC/4 + 255)/256, 256, 0, stream>>>(feat, xb, T_STEPS*NC/4);

  hist_kernel<<<dim3(BHIST, T_STEPS), 512, 0, stream>>>(edges, histP);
  reduce_scan_kernel<<<dim3(NCHK, T_STEPS), 256, 0, stream>>>(histP, rowptr_all, chunk_tot, dinv_all);
  scanb_kernel<<<T_STEPS, 64, 0, stream>>>(chunk_tot, chunk_base, rowptr_all);
  scanc_kernel<<<dim3(NCHK, T_STEPS), 256, 0, stream>>>(rowptr_all, chunk_base);
  place_kernel<<<dim3(PRS*PES, T_STEPS), 512, 0, stream>>>(edges, rowptr_all, histP, colA_all);

  for (int t=0; t<T_STEPS; ++t){
    const int*   rowptr = rowptr_all + (size_t)t*(NN+1);
    const u16*   colA   = colA_all + (size_t)t*EE;
    const float* dinv   = dinv_all + (size_t)t*NN;
    const u16*   x      = xb + (size_t)t*NC;

    spmm2_kernel<<<dim3(2*(NN/4)), 256, 0, stream>>>(rowptr,colA,dinv, x,a1x, h,a1h);
    spmm2_kernel<<<dim3(2*(NN/4)), 256, 0, stream>>>(rowptr,colA,dinv, a1x,a2x, a1h,a2h);

    mgemm_kernel<6,768,1,6><<<dim3(8*20*6), 256, 0, stream>>>(
        x,a1x,a2x,h,a1h,a2h, WbigT, bz, br, h, zbuf, chx, hr, nullptr, nullptr);

    spmm_kernel<<<dim3(NN/4), 256, 0, stream>>>(rowptr,colA,dinv, hr, a1x);
    spmm_kernel<<<dim3(NN/4), 256, 0, stream>>>(rowptr,colA,dinv, a1x, a2x);

    mgemm_kernel<3,384,2,2><<<dim3(8*20*2), 256, 0, stream>>>(
        hr,a1x,a2x,nullptr,nullptr,nullptr, WrT, bht, nullptr, h, zbuf, chx,
        nullptr, h, nullptr);
  }

  mgemm_kernel<1,128,0,0><<<dim3(157,1), 256, 0, stream>>>(
      h,nullptr,nullptr,nullptr,nullptr,nullptr, WpT, bp, nullptr,
      nullptr, nullptr, nullptr, nullptr, nullptr, out);
}

// Round 14
// 898.756 us; speedup vs baseline: 1.0277x; 1.0277x over previous
//
#include <hip/hip_runtime.h>

#define T_STEPS 10
#define NN 10000
#define EE 320000
#define CC 128
#define NC (NN*CC)
#define BHIST 32
#define EPB (EE/BHIST)   // 10000 edges per hist/place block
#define NCHK 40          // ceil(NN/256) scan chunks

typedef unsigned short u16;
typedef unsigned int u32;
typedef __attribute__((ext_vector_type(8))) short bf16x8;
typedef __attribute__((ext_vector_type(4))) float f32x4;

__device__ __forceinline__ float sigmoidf_(float x){ return 1.f/(1.f+__expf(-x)); }
__device__ __forceinline__ float tanhf_(float x){
  x = fminf(15.f, fmaxf(-15.f, x));
  float e = __expf(2.f*x);
  return (e-1.f)/(e+1.f);
}
__device__ __forceinline__ u16 f2bf(float f){
  u32 u = __float_as_uint(f);
  u32 r = u + 0x7fffu + ((u>>16)&1u);
  return (u16)(r>>16);
}
__device__ __forceinline__ float bf2f(u16 s){
  return __uint_as_float(((u32)s)<<16);
}
__device__ __forceinline__ float blo(u32 u){ return __uint_as_float(u<<16); }
__device__ __forceinline__ float bhi(u32 u){ return __uint_as_float(u & 0xffff0000u); }
__device__ __forceinline__ void gload16(const void* g, void* l){
  __builtin_amdgcn_global_load_lds(
    (const __attribute__((address_space(1))) void*)g,
    (__attribute__((address_space(3))) void*)l, 16, 0, 0);
}

// ---------------- prep: transposed bf16 effective weights + biases + h0 -----
__global__ __launch_bounds__(256) void prep_kernel(
    const float* __restrict__ Wxz, const float* __restrict__ Whz,
    const float* __restrict__ Wxr, const float* __restrict__ Whr,
    const float* __restrict__ Wxh, const float* __restrict__ Whh,
    const float* __restrict__ bxz, const float* __restrict__ bhz,
    const float* __restrict__ bxr, const float* __restrict__ bhr,
    const float* __restrict__ bxh, const float* __restrict__ bhh,
    const float* __restrict__ Wp,
    u16* __restrict__ WbigT, u16* __restrict__ WrT, u16* __restrict__ WpT,
    float* __restrict__ bz, float* __restrict__ br, float* __restrict__ bht,
    u16* __restrict__ h)
{
  int idx = blockIdx.x*256 + threadIdx.x;
  if (idx < NC) h[idx] = 0;
  if (idx < 384*768) {
    int c = idx / 768, k = idx - c*768;
    int gate = c >> 7, cc = c & 127;
    int hside = (k >= 384);
    int kk = hside ? k - 384 : k;
    int blk = kk >> 7, row = kk & 127;
    const float* W = nullptr;
    if (!hside) W = (gate==0) ? Wxz : (gate==1) ? Wxr : Wxh;
    else if (gate==0) W = Whz; else if (gate==1) W = Whr;
    float v = 0.f;
    if (W) {
      int base = row*CC + cc;
      float w0 = W[base], w1 = W[CC*CC + base], w2 = W[2*CC*CC + base];
      v = (blk==0) ? (w0 - w2) : (blk==1) ? w1 : (2.f*w2);
    }
    WbigT[idx] = f2bf(v);
  }
  if (idx < 128*384) {
    int c = idx / 384, k = idx - c*384;
    int blk = k >> 7, row = k & 127;
    int base = row*CC + c;
    float w0 = Whh[base], w1 = Whh[CC*CC+base], w2 = Whh[2*CC*CC+base];
    WrT[idx] = f2bf((blk==0) ? (w0-w2) : (blk==1) ? w1 : (2.f*w2));
  }
  if (idx < 64*128) {
    int c = idx >> 7, k = idx & 127;
    WpT[idx] = f2bf(Wp[k*64 + c]);
  }
  if (idx < CC) {
    bz[idx]  = bxz[idx] + bhz[idx];
    br[idx]  = bxr[idx] + bhr[idx];
    bht[idx] = bxh[idx] + bhh[idx];
  }
}

// fp32 -> bf16, 4 elems/thread; n4 = number of float4 chunks
__global__ __launch_bounds__(256) void xconv_kernel(const float* __restrict__ x, u16* __restrict__ xb, int n4){
  int i = blockIdx.x*256 + threadIdx.x;
  if (i >= n4) return;
  long long o = (long long)i*4;
  float4 v = *(const float4*)(x + o);
  u32 u0 = (u32)f2bf(v.x) | ((u32)f2bf(v.y)<<16);
  u32 u1 = (u32)f2bf(v.z) | ((u32)f2bf(v.w)<<16);
  uint2 r; r.x=u0; r.y=u1;
  *(uint2*)(xb + o) = r;
}

// ---------------- graph build: packed LDS histograms, zero global atomics --
__global__ __launch_bounds__(512) void hist_kernel(const int* __restrict__ edges,
                                                   u32* __restrict__ histP){
  __shared__ u32 hist[NN];   // 40 KB
  int t = blockIdx.y, b = blockIdx.x, tid = threadIdx.x;
  for (int i = tid; i < NN; i += 512) hist[i] = 0;
  __syncthreads();
  const int* src = edges + (size_t)t*2*EE;
  const int* dst = src + EE;
  int e1 = b*EPB + EPB;
  #pragma unroll 4
  for (int e = b*EPB + tid; e < e1; e += 512){
    int s = src[e], d = dst[e];
    if (s != d){
      atomicAdd(&hist[s], 1u);         // ds_add, LDS-local
      atomicAdd(&hist[d], 1u << 16);
    }
  }
  __syncthreads();
  u32* hp = histP + ((size_t)t*BHIST + b)*NN;
  for (int i = tid; i < NN; i += 512) hp[i] = hist[i];
}

// reduce+chunk-scan: per (t,chunk of 256 nodes): deg->dinv; per-block cnt
// exclusive prefix into partial high16; chunk-local exclusive scan into
// rowptr; chunk totals out.
__global__ __launch_bounds__(256) void reduce_scan_kernel(u32* __restrict__ histP,
                                                          int* __restrict__ rowptr_all,
                                                          int* __restrict__ chunk_tot,
                                                          float* __restrict__ dinv_all){
  int t = blockIdx.y, ch = blockIdx.x, tid = threadIdx.x;
  int d = ch*256 + tid;
  u32 run=0, degs=0;
  if (d < NN){
    size_t base = (size_t)t*BHIST*NN + d;
    #pragma unroll
    for (int b=0;b<BHIST;++b){
      size_t ix = base + (size_t)b*NN;
      u32 v = histP[ix];
      histP[ix] = (v & 0xffffu) | (run<<16);
      run += v>>16;
      degs += v & 0xffffu;
    }
    dinv_all[t*NN+d] = degs>0 ? rsqrtf((float)degs) : 0.f;
  }
  int lane = tid&63, wv = tid>>6;
  int s = (int)run;
  #pragma unroll
  for (int off=1; off<64; off<<=1){
    int u = __shfl_up(s, off, 64);
    if (lane>=off) s += u;
  }
  __shared__ int wsum[4];
  if (lane==63) wsum[wv] = s;
  __syncthreads();
  int add = 0;
  #pragma unroll
  for (int w=0; w<3; ++w) if (w < wv) add += wsum[w];
  int incl = s + add;
  if (d < NN) rowptr_all[(size_t)t*(NN+1)+d] = incl - (int)run;
  if (tid==255) chunk_tot[t*NCHK + ch] = incl;
}

// scan of NCHK chunk totals per t (one wave)
__global__ __launch_bounds__(64) void scanb_kernel(const int* __restrict__ chunk_tot,
                                                   int* __restrict__ chunk_base,
                                                   int* __restrict__ rowptr_all){
  int t = blockIdx.x; int lane = threadIdx.x;
  int v = (lane < NCHK) ? chunk_tot[t*NCHK+lane] : 0;
  int s = v;
  #pragma unroll
  for (int off=1; off<64; off<<=1){
    int u = __shfl_up(s, off, 64);
    if (lane>=off) s += u;
  }
  if (lane < NCHK) chunk_base[t*NCHK+lane] = s - v;
  if (lane == NCHK-1) rowptr_all[(size_t)t*(NN+1)+NN] = s;
}

__global__ __launch_bounds__(256) void scanc_kernel(int* __restrict__ rowptr_all,
                                                    const int* __restrict__ chunk_base){
  int t = blockIdx.y, ch = blockIdx.x;
  int d = ch*256 + threadIdx.x;
  if (d < NN) rowptr_all[(size_t)t*(NN+1)+d] += chunk_base[t*NCHK+ch];
}

// place (r12 version, proven ~50us): counting-sort scatter. LDS counters
// seeded with rowptr + per-block exclusive base; rank via LDS atomics.
__global__ __launch_bounds__(512) void place_kernel(const int* __restrict__ edges,
                                                    const int* __restrict__ rowptr_all,
                                                    const u32* __restrict__ histP,
                                                    u16* __restrict__ colA_all){
  __shared__ int slot[NN];     // 40 KB
  int t = blockIdx.y, b = blockIdx.x, tid = threadIdx.x;
  const int* rowptr = rowptr_all + (size_t)t*(NN+1);
  const u32* hp = histP + ((size_t)t*BHIST + b)*NN;
  for (int i = tid; i < NN; i += 512) slot[i] = rowptr[i] + (int)(hp[i] >> 16);
  __syncthreads();
  const int* src = edges + (size_t)t*2*EE;
  const int* dst = src + EE;
  u16* colA = colA_all + (size_t)t*EE;
  int e1 = b*EPB + EPB;
  #pragma unroll 4
  for (int e = b*EPB + tid; e < e1; e += 512){
    int s = src[e], d = dst[e];
    if (s != d){
      int pos = atomicAdd(&slot[d], 1);   // LDS atomic, returns rank
      colA[pos] = (u16)s;
    }
  }
}

// ---------------- CSR SpMM core: quad-edge, one wave per row ---------------
// 4 lane-groups of 16; group q processes edges k0+q, k0+q+4, ...; each group
// covers all 128 channels via uint4 -> 4 edges in flight, trips/4.
// Merge via shfl_xor(16)+shfl_xor(32); group 0 writes 16B.
__device__ __forceinline__ void spmm_row4(const int* __restrict__ rowptr, const u16* __restrict__ colA,
                                          const float* __restrict__ dinv,
                                          const u16* __restrict__ in, u16* __restrict__ out,
                                          int wb, int wave, int lane){
  int row = wb*4 + wave;
  int k0 = rowptr[row], k1 = rowptr[row+1];
  int q = lane >> 4, cl = lane & 15;      // channels 8cl..8cl+7
  float a0=0.f,a1=0.f,a2=0.f,a3=0.f,a4=0.f,a5=0.f,a6=0.f,a7=0.f;
  #pragma unroll 2
  for (int k = k0 + q; k < k1; k += 4){
    int s = colA[k];
    float w = dinv[s];
    uint4 u = *(const uint4*)(in + (size_t)s*CC + cl*8);
    a0 = fmaf(w, blo(u.x), a0);  a1 = fmaf(w, bhi(u.x), a1);
    a2 = fmaf(w, blo(u.y), a2);  a3 = fmaf(w, bhi(u.y), a3);
    a4 = fmaf(w, blo(u.z), a4);  a5 = fmaf(w, bhi(u.z), a5);
    a6 = fmaf(w, blo(u.w), a6);  a7 = fmaf(w, bhi(u.w), a7);
  }
  a0 += __shfl_xor(a0,16); a1 += __shfl_xor(a1,16);
  a2 += __shfl_xor(a2,16); a3 += __shfl_xor(a3,16);
  a4 += __shfl_xor(a4,16); a5 += __shfl_xor(a5,16);
  a6 += __shfl_xor(a6,16); a7 += __shfl_xor(a7,16);
  a0 += __shfl_xor(a0,32); a1 += __shfl_xor(a1,32);
  a2 += __shfl_xor(a2,32); a3 += __shfl_xor(a3,32);
  a4 += __shfl_xor(a4,32); a5 += __shfl_xor(a5,32);
  a6 += __shfl_xor(a6,32); a7 += __shfl_xor(a7,32);
  if (q == 0){
    float wrow = -dinv[row];
    uint4 r;
    r.x = (u32)f2bf(wrow*a0) | ((u32)f2bf(wrow*a1)<<16);
    r.y = (u32)f2bf(wrow*a2) | ((u32)f2bf(wrow*a3)<<16);
    r.z = (u32)f2bf(wrow*a4) | ((u32)f2bf(wrow*a5)<<16);
    r.w = (u32)f2bf(wrow*a6) | ((u32)f2bf(wrow*a7)<<16);
    *(uint4*)(out + (size_t)row*CC + cl*8) = r;
  }
}

// single-input SpMM (h chain, hr chain)
__global__ __launch_bounds__(256) void spmm_kernel(const int* __restrict__ rowptr, const u16* __restrict__ colA,
                                                   const float* __restrict__ dinv,
                                                   const u16* __restrict__ in, u16* __restrict__ out){
  int wave = threadIdx.x >> 6, lane = threadIdx.x & 63;
  int wb = blockIdx.x;
  if (wb >= NN/4) return;
  spmm_row4(rowptr, colA, dinv, in, out, wb, wave, lane);
}

// batched x-chain SpMM over all timesteps, XCD-PINNED per t (r6's hoist
// failed from L2 thrash across 10 concurrent t's; pinning bid&7 -> one t
// per XCD keeps each XCD's gather working set to one 2.5MB matrix).
// 25000 blocks: xcd<8 serves t=xcd for j<2500; tail j>=2500: xcd groups
// of 4 serve t=8,9.
__global__ __launch_bounds__(256) void bxchain_kernel(const int* __restrict__ rowptr_all,
                                                      const u16* __restrict__ colA_all,
                                                      const float* __restrict__ dinv_all,
                                                      const u16* __restrict__ in_all,
                                                      u16* __restrict__ out_all){
  int lane = threadIdx.x & 63, wave = threadIdx.x >> 6;
  int bid = blockIdx.x;
  int xcd = bid & 7;
  int j = bid >> 3;                 // 0..3124
  int t, wb;
  if (j < 2500){ t = xcd; wb = j; }
  else { t = 8 + (xcd >> 2); wb = (j - 2500)*4 + (xcd & 3); }
  const int*   rowptr = rowptr_all + (size_t)t*(NN+1);
  const u16*   colA   = colA_all + (size_t)t*EE;
  const float* dinv   = dinv_all + (size_t)t*NN;
  spmm_row4(rowptr, colA, dinv, in_all + (size_t)t*NC, out_all + (size_t)t*NC,
            wb, wave, lane);
}

// ---------------- bf16 MFMA GEMM over segmented K, BK=128 ------------------
// BM=BN=64, BK=128 (one segment per staging round); 4 waves/block, each a
// 32x32 quadrant. LDS [64 rows][16 x 16B chunks], XOR swizzle chunk^=(row&15),
// staged by global_load_lds with pre-swizzled SOURCE (both-sides rule #21).
// SWZN>0: 1D grid 8*20*SWZN, XCD bid&7 owns a contiguous 20-m-tile stripe.
// EPI 1 + n0>=256 (h~ cols): h-side B rows structurally zero -> K-skip.
template<int NSEG, int KDIM, int EPI, int SWZN>
__global__ __launch_bounds__(256) void mgemm_kernel(
    const u16* __restrict__ A0, const u16* __restrict__ A1, const u16* __restrict__ A2,
    const u16* __restrict__ A3, const u16* __restrict__ A4, const u16* __restrict__ A5,
    const u16* __restrict__ Bt,
    const float* __restrict__ bias0, const float* __restrict__ bias1,
    const u16* __restrict__ hbuf,
    float* __restrict__ zbuf, float* __restrict__ chx,
    u16* __restrict__ hr_out, u16* __restrict__ h_out,
    float* __restrict__ out_f)
{
  __shared__ __align__(16) u16 As[64*128];
  __shared__ __align__(16) u16 Bs[64*128];
  const u16* segs[6] = {A0,A1,A2,A3,A4,A5};
  int tid = threadIdx.x, lane = tid & 63, wvi = tid >> 6;
  int m0, n0;
  if (SWZN > 0){
    int bid = blockIdx.x;
    int j = bid >> 3;
    int mt = (bid & 7)*20 + (j % 20);
    if (mt >= 157) return;
    m0 = mt*64; n0 = (j/20)*64;
  } else {
    m0 = blockIdx.x*64; n0 = blockIdx.y*64;
  }
  int wr = wvi >> 1, wc = wvi & 1;

  f32x4 acc[2][2] = {};

  int c_lo = wvi*64 + lane;
  int rl = lane & 15, rg = lane >> 4;
  int offA[2][4], offB[2][4];
  #pragma unroll
  for (int mf=0; mf<2; ++mf)
    #pragma unroll
    for (int ks=0; ks<4; ++ks){
      offA[mf][ks] = (wr*32 + mf*16 + rl)*256 + ((((ks<<2)+rg) ^ rl)<<4);
      offB[mf][ks] = (wc*32 + mf*16 + rl)*256 + ((((ks<<2)+rg) ^ rl)<<4);
    }

  const int ktend = (EPI==1 && n0 >= 256) ? (NSEG/2) : NSEG;  // K-skip h~ cols
  for (int kt=0; kt<ktend; ++kt){
    const u16* __restrict__ Aseg = segs[kt];
    __syncthreads();
    #pragma unroll
    for (int i=0;i<4;++i){
      int c = i*256 + c_lo;
      int row = c >> 4, slot = c & 15;
      int scw = slot ^ (row & 15);
      int grow = m0 + row; if (grow > NN-1) grow = NN-1;
      gload16(Aseg + (size_t)grow*CC + scw*8,
              (u16*)As + ((size_t)i*256 + wvi*64)*8);
      gload16(Bt + (size_t)(n0 + row)*KDIM + kt*128 + scw*8,
              (u16*)Bs + ((size_t)i*256 + wvi*64)*8);
    }
    __syncthreads();
    #pragma unroll
    for (int ks=0; ks<4; ++ks){
      bf16x8 a0 = *(const bf16x8*)((const char*)As + offA[0][ks]);
      bf16x8 a1 = *(const bf16x8*)((const char*)As + offA[1][ks]);
      bf16x8 b0 = *(const bf16x8*)((const char*)Bs + offB[0][ks]);
      bf16x8 b1 = *(const bf16x8*)((const char*)Bs + offB[1][ks]);
      acc[0][0] = __builtin_amdgcn_mfma_f32_16x16x32_bf16(a0, b0, acc[0][0], 0,0,0);
      acc[0][1] = __builtin_amdgcn_mfma_f32_16x16x32_bf16(a0, b1, acc[0][1], 0,0,0);
      acc[1][0] = __builtin_amdgcn_mfma_f32_16x16x32_bf16(a1, b0, acc[1][0], 0,0,0);
      acc[1][1] = __builtin_amdgcn_mfma_f32_16x16x32_bf16(a1, b1, acc[1][1], 0,0,0);
    }
  }

  // epilogue: C/D layout col=lane&15, row=(lane>>4)*4+reg  [guide m89]
  #pragma unroll
  for (int mf=0; mf<2; ++mf){
    #pragma unroll
    for (int nf=0; nf<2; ++nf){
      #pragma unroll
      for (int r=0; r<4; ++r){
        int grow = m0 + wr*32 + mf*16 + rg*4 + r;
        if (grow >= NN) continue;
        int gcol = n0 + wc*32 + nf*16 + rl;
        float v = acc[mf][nf][r];
        if (EPI==0){
          out_f[(size_t)grow*64 + gcol] = v + bias0[gcol];
        } else if (EPI==1){
          int gate = gcol >> 7, c = gcol & 127;
          size_t idx = (size_t)grow*CC + c;
          if (gate==0)      zbuf[idx] = sigmoidf_(v + bias0[c]);
          else if (gate==1){
            float rr = sigmoidf_(v + bias1[c]);
            hr_out[idx] = f2bf(rr * bf2f(hbuf[idx]));
          } else            chx[idx] = v;
        } else {
          size_t idx = (size_t)grow*CC + gcol;
          float pre = v + chx[idx] + bias0[gcol];
          float ht = tanhf_(pre);
          float zz = zbuf[idx];
          float hv = bf2f(hbuf[idx]);
          h_out[idx] = f2bf(fmaf(zz, hv - ht, ht));
        }
      }
    }
  }
}

extern "C" void kernel_launch(void* const* d_in, const int* in_sizes, int n_in,
                              void* d_out, int out_size, void* d_ws, size_t ws_size,
                              hipStream_t stream)
{
  (void)in_sizes; (void)n_in; (void)out_size; (void)ws_size;
  const float* feat = (const float*)d_in[0];
  const int*   edges = (const int*)d_in[1];
  const float* Wxz=(const float*)d_in[2];  const float* bxz=(const float*)d_in[3];
  const float* Whz=(const float*)d_in[4];  const float* bhz=(const float*)d_in[5];
  const float* Wxr=(const float*)d_in[6];  const float* bxr=(const float*)d_in[7];
  const float* Whr=(const float*)d_in[8];  const float* bhr=(const float*)d_in[9];
  const float* Wxh=(const float*)d_in[10]; const float* bxh=(const float*)d_in[11];
  const float* Whh=(const float*)d_in[12]; const float* bhh=(const float*)d_in[13];
  const float* Wp =(const float*)d_in[14]; const float* bp =(const float*)d_in[15];
  float* out = (float*)d_out;

  char* p = (char*)d_ws;
  auto alloc = [&](size_t bytes)->char* {
    char* r = p; p += (bytes + 255) & ~(size_t)255; return r;
  };
  u16* xb     = (u16*)alloc((size_t)T_STEPS*NC*2);
  u16* a1xA   = (u16*)alloc((size_t)T_STEPS*NC*2);
  u16* a2xA   = (u16*)alloc((size_t)T_STEPS*NC*2);
  u16* h    = (u16*)alloc((size_t)NC*2);
  u16* a1h  = (u16*)alloc((size_t)NC*2);
  u16* a2h  = (u16*)alloc((size_t)NC*2);
  u16* hr   = (u16*)alloc((size_t)NC*2);
  float* zbuf = (float*)alloc((size_t)NC*4);
  float* chx  = (float*)alloc((size_t)NC*4);
  u16* WbigT = (u16*)alloc(384*768*2);
  u16* WrT   = (u16*)alloc(128*384*2);
  u16* WpT   = (u16*)alloc(64*128*2);
  float* bz  = (float*)alloc(CC*4);
  float* br  = (float*)alloc(CC*4);
  float* bht = (float*)alloc(CC*4);
  float* dinv_all = (float*)alloc((size_t)T_STEPS*NN*4);
  int* rowptr_all = (int*)alloc((size_t)T_STEPS*(NN+1)*4);
  u16* colA_all   = (u16*)alloc((size_t)T_STEPS*EE*2);
  int* chunk_tot  = (int*)alloc((size_t)T_STEPS*NCHK*4);
  int* chunk_base = (int*)alloc((size_t)T_STEPS*NCHK*4);
  // packed hist partials (12.8MB) alias hr+zbuf+chx (contiguous exact-256B
  // sizes; dead before the recurrence loop first writes them)
  u32* histP = (u32*)hr;

  prep_kernel<<<NC/256, 256, 0, stream>>>(Wxz,Whz,Wxr,Whr,Wxh,Whh,
                                          bxz,bhz,bxr,bhr,bxh,bhh, Wp,
                                          WbigT, WrT, WpT, bz, br, bht, h);
  xconv_kernel<<<(T_STEPS*NC/4 + 255)/256, 256, 0, stream>>>(feat, xb, T_STEPS*NC/4);

  hist_kernel<<<dim3(BHIST, T_STEPS), 512, 0, stream>>>(edges, histP);
  reduce_scan_kernel<<<dim3(NCHK, T_STEPS), 256, 0, stream>>>(histP, rowptr_all, chunk_tot, dinv_all);
  scanb_kernel<<<T_STEPS, 64, 0, stream>>>(chunk_tot, chunk_base, rowptr_all);
  scanc_kernel<<<dim3(NCHK, T_STEPS), 256, 0, stream>>>(rowptr_all, chunk_base);
  place_kernel<<<dim3(BHIST, T_STEPS), 512, 0, stream>>>(edges, rowptr_all, histP, colA_all);

  // XCD-pinned batched x-chain (recurrence-independent): Lx, L^2x for all t
  bxchain_kernel<<<dim3(25000), 256, 0, stream>>>(rowptr_all, colA_all, dinv_all, xb, a1xA);
  bxchain_kernel<<<dim3(25000), 256, 0, stream>>>(rowptr_all, colA_all, dinv_all, a1xA, a2xA);

  for (int t=0; t<T_STEPS; ++t){
    const int*   rowptr = rowptr_all + (size_t)t*(NN+1);
    const u16*   colA   = colA_all + (size_t)t*EE;
    const float* dinv   = dinv_all + (size_t)t*NN;
    const u16*   x      = xb + (size_t)t*NC;
    u16* a1x = a1xA + (size_t)t*NC;   // dead after gemm1 -> reused by hr chain
    u16* a2x = a2xA + (size_t)t*NC;

    spmm_kernel<<<dim3(NN/4), 256, 0, stream>>>(rowptr,colA,dinv, h, a1h);
    spmm_kernel<<<dim3(NN/4), 256, 0, stream>>>(rowptr,colA,dinv, a1h, a2h);

    mgemm_kernel<6,768,1,6><<<dim3(8*20*6), 256, 0, stream>>>(
        x,a1x,a2x,h,a1h,a2h, WbigT, bz, br, h, zbuf, chx, hr, nullptr, nullptr);

    spmm_kernel<<<dim3(NN/4), 256, 0, stream>>>(rowptr,colA,dinv, hr, a1x);
    spmm_kernel<<<dim3(NN/4), 256, 0, stream>>>(rowptr,colA,dinv, a1x, a2x);

    mgemm_kernel<3,384,2,2><<<dim3(8*20*2), 256, 0, stream>>>(
        hr,a1x,a2x,nullptr,nullptr,nullptr, WrT, bht, nullptr, h, zbuf, chx,
        nullptr, h, nullptr);
  }

  mgemm_kernel<1,128,0,0><<<dim3(157,1), 256, 0, stream>>>(
      h,nullptr,nullptr,nullptr,nullptr,nullptr, WpT, bp, nullptr,
      nullptr, nullptr, nullptr, nullptr, nullptr, out);
}

// Round 15
// 883.629 us; speedup vs baseline: 1.0453x; 1.0171x over previous
//
#include <hip/hip_runtime.h>

#define T_STEPS 10
#define NN 10000
#define EE 320000
#define CC 128
#define NC (NN*CC)
#define BHIST 32
#define EPB (EE/BHIST)   // 10000 edges per hist/place block
#define NCHK 40          // ceil(NN/256) scan chunks

typedef unsigned short u16;
typedef unsigned int u32;
typedef __attribute__((ext_vector_type(8))) short bf16x8;
typedef __attribute__((ext_vector_type(4))) float f32x4;

__device__ __forceinline__ float sigmoidf_(float x){ return 1.f/(1.f+__expf(-x)); }
__device__ __forceinline__ float tanhf_(float x){
  x = fminf(15.f, fmaxf(-15.f, x));
  float e = __expf(2.f*x);
  return (e-1.f)/(e+1.f);
}
__device__ __forceinline__ u16 f2bf(float f){
  u32 u = __float_as_uint(f);
  u32 r = u + 0x7fffu + ((u>>16)&1u);
  return (u16)(r>>16);
}
__device__ __forceinline__ float bf2f(u16 s){
  return __uint_as_float(((u32)s)<<16);
}
__device__ __forceinline__ float blo(u32 u){ return __uint_as_float(u<<16); }
__device__ __forceinline__ float bhi(u32 u){ return __uint_as_float(u & 0xffff0000u); }
__device__ __forceinline__ void gload16(const void* g, void* l){
  __builtin_amdgcn_global_load_lds(
    (const __attribute__((address_space(1))) void*)g,
    (__attribute__((address_space(3))) void*)l, 16, 0, 0);
}

// ---------------- prep: transposed bf16 effective weights + biases + h0 -----
__global__ __launch_bounds__(256) void prep_kernel(
    const float* __restrict__ Wxz, const float* __restrict__ Whz,
    const float* __restrict__ Wxr, const float* __restrict__ Whr,
    const float* __restrict__ Wxh, const float* __restrict__ Whh,
    const float* __restrict__ bxz, const float* __restrict__ bhz,
    const float* __restrict__ bxr, const float* __restrict__ bhr,
    const float* __restrict__ bxh, const float* __restrict__ bhh,
    const float* __restrict__ Wp,
    u16* __restrict__ WbigT, u16* __restrict__ WrT, u16* __restrict__ WpT,
    float* __restrict__ bz, float* __restrict__ br, float* __restrict__ bht,
    u16* __restrict__ h)
{
  int idx = blockIdx.x*256 + threadIdx.x;
  if (idx < NC) h[idx] = 0;
  if (idx < 384*768) {
    int c = idx / 768, k = idx - c*768;
    int gate = c >> 7, cc = c & 127;
    int hside = (k >= 384);
    int kk = hside ? k - 384 : k;
    int blk = kk >> 7, row = kk & 127;
    const float* W = nullptr;
    if (!hside) W = (gate==0) ? Wxz : (gate==1) ? Wxr : Wxh;
    else if (gate==0) W = Whz; else if (gate==1) W = Whr;
    float v = 0.f;
    if (W) {
      int base = row*CC + cc;
      float w0 = W[base], w1 = W[CC*CC + base], w2 = W[2*CC*CC + base];
      v = (blk==0) ? (w0 - w2) : (blk==1) ? w1 : (2.f*w2);
    }
    WbigT[idx] = f2bf(v);
  }
  if (idx < 128*384) {
    int c = idx / 384, k = idx - c*384;
    int blk = k >> 7, row = k & 127;
    int base = row*CC + c;
    float w0 = Whh[base], w1 = Whh[CC*CC+base], w2 = Whh[2*CC*CC+base];
    WrT[idx] = f2bf((blk==0) ? (w0-w2) : (blk==1) ? w1 : (2.f*w2));
  }
  if (idx < 64*128) {
    int c = idx >> 7, k = idx & 127;
    WpT[idx] = f2bf(Wp[k*64 + c]);
  }
  if (idx < CC) {
    bz[idx]  = bxz[idx] + bhz[idx];
    br[idx]  = bxr[idx] + bhr[idx];
    bht[idx] = bxh[idx] + bhh[idx];
  }
}

// fp32 -> bf16, 4 elems/thread; n4 = number of float4 chunks
__global__ __launch_bounds__(256) void xconv_kernel(const float* __restrict__ x, u16* __restrict__ xb, int n4){
  int i = blockIdx.x*256 + threadIdx.x;
  if (i >= n4) return;
  long long o = (long long)i*4;
  float4 v = *(const float4*)(x + o);
  u32 u0 = (u32)f2bf(v.x) | ((u32)f2bf(v.y)<<16);
  u32 u1 = (u32)f2bf(v.z) | ((u32)f2bf(v.w)<<16);
  uint2 r; r.x=u0; r.y=u1;
  *(uint2*)(xb + o) = r;
}

// ---------------- graph build: packed LDS histograms, zero global atomics --
__global__ __launch_bounds__(512) void hist_kernel(const int* __restrict__ edges,
                                                   u32* __restrict__ histP){
  __shared__ u32 hist[NN];   // 40 KB
  int t = blockIdx.y, b = blockIdx.x, tid = threadIdx.x;
  for (int i = tid; i < NN; i += 512) hist[i] = 0;
  __syncthreads();
  const int* src = edges + (size_t)t*2*EE;
  const int* dst = src + EE;
  int e1 = b*EPB + EPB;
  #pragma unroll 4
  for (int e = b*EPB + tid; e < e1; e += 512){
    int s = src[e], d = dst[e];
    if (s != d){
      atomicAdd(&hist[s], 1u);         // ds_add, LDS-local
      atomicAdd(&hist[d], 1u << 16);
    }
  }
  __syncthreads();
  u32* hp = histP + ((size_t)t*BHIST + b)*NN;
  for (int i = tid; i < NN; i += 512) hp[i] = hist[i];
}

// reduce+chunk-scan: per (t,chunk of 256 nodes): deg->dinv; per-block cnt
// exclusive prefix into partial high16; chunk-local exclusive scan into
// rowptr; chunk totals out.
__global__ __launch_bounds__(256) void reduce_scan_kernel(u32* __restrict__ histP,
                                                          int* __restrict__ rowptr_all,
                                                          int* __restrict__ chunk_tot,
                                                          float* __restrict__ dinv_all){
  int t = blockIdx.y, ch = blockIdx.x, tid = threadIdx.x;
  int d = ch*256 + tid;
  u32 run=0, degs=0;
  if (d < NN){
    size_t base = (size_t)t*BHIST*NN + d;
    #pragma unroll
    for (int b=0;b<BHIST;++b){
      size_t ix = base + (size_t)b*NN;
      u32 v = histP[ix];
      histP[ix] = (v & 0xffffu) | (run<<16);
      run += v>>16;
      degs += v & 0xffffu;
    }
    dinv_all[t*NN+d] = degs>0 ? rsqrtf((float)degs) : 0.f;
  }
  int lane = tid&63, wv = tid>>6;
  int s = (int)run;
  #pragma unroll
  for (int off=1; off<64; off<<=1){
    int u = __shfl_up(s, off, 64);
    if (lane>=off) s += u;
  }
  __shared__ int wsum[4];
  if (lane==63) wsum[wv] = s;
  __syncthreads();
  int add = 0;
  #pragma unroll
  for (int w=0; w<3; ++w) if (w < wv) add += wsum[w];
  int incl = s + add;
  if (d < NN) rowptr_all[(size_t)t*(NN+1)+d] = incl - (int)run;
  if (tid==255) chunk_tot[t*NCHK + ch] = incl;
}

// scan of NCHK chunk totals per t (one wave)
__global__ __launch_bounds__(64) void scanb_kernel(const int* __restrict__ chunk_tot,
                                                   int* __restrict__ chunk_base,
                                                   int* __restrict__ rowptr_all){
  int t = blockIdx.x; int lane = threadIdx.x;
  int v = (lane < NCHK) ? chunk_tot[t*NCHK+lane] : 0;
  int s = v;
  #pragma unroll
  for (int off=1; off<64; off<<=1){
    int u = __shfl_up(s, off, 64);
    if (lane>=off) s += u;
  }
  if (lane < NCHK) chunk_base[t*NCHK+lane] = s - v;
  if (lane == NCHK-1) rowptr_all[(size_t)t*(NN+1)+NN] = s;
}

__global__ __launch_bounds__(256) void scanc_kernel(int* __restrict__ rowptr_all,
                                                    const int* __restrict__ chunk_base){
  int t = blockIdx.y, ch = blockIdx.x;
  int d = ch*256 + threadIdx.x;
  if (d < NN) rowptr_all[(size_t)t*(NN+1)+d] += chunk_base[t*NCHK+ch];
}

// place (r12 version, proven ~50us): counting-sort scatter. LDS counters
// seeded with rowptr + per-block exclusive base; rank via LDS atomics.
__global__ __launch_bounds__(512) void place_kernel(const int* __restrict__ edges,
                                                    const int* __restrict__ rowptr_all,
                                                    const u32* __restrict__ histP,
                                                    u16* __restrict__ colA_all){
  __shared__ int slot[NN];     // 40 KB
  int t = blockIdx.y, b = blockIdx.x, tid = threadIdx.x;
  const int* rowptr = rowptr_all + (size_t)t*(NN+1);
  const u32* hp = histP + ((size_t)t*BHIST + b)*NN;
  for (int i = tid; i < NN; i += 512) slot[i] = rowptr[i] + (int)(hp[i] >> 16);
  __syncthreads();
  const int* src = edges + (size_t)t*2*EE;
  const int* dst = src + EE;
  u16* colA = colA_all + (size_t)t*EE;
  int e1 = b*EPB + EPB;
  #pragma unroll 4
  for (int e = b*EPB + tid; e < e1; e += 512){
    int s = src[e], d = dst[e];
    if (s != d){
      int pos = atomicAdd(&slot[d], 1);   // LDS atomic, returns rank
      colA[pos] = (u16)s;
    }
  }
}

// ---------------- CSR SpMM core: oct-edge, one wave per row ----------------
// 8 lane-groups of 8; group q processes edges k0+q, k0+q+8, ...; each group
// covers all 128 channels via 2x uint4 (32B x 8 lanes = 256B row) -> 8 edges
// in flight, trips/8. Merge via shfl_xor(8,16,32); group 0 writes 32B.
// -dinv[row] applied once at the end.
__device__ __forceinline__ void spmm_row4(const int* __restrict__ rowptr, const u16* __restrict__ colA,
                                          const float* __restrict__ dinv,
                                          const u16* __restrict__ in, u16* __restrict__ out,
                                          int wb, int wave, int lane){
  int row = wb*4 + wave;
  int k0 = rowptr[row], k1 = rowptr[row+1];
  int q = lane >> 3, cl = lane & 7;      // channels 16cl..16cl+15
  float a[16];
  #pragma unroll
  for (int i=0;i<16;++i) a[i]=0.f;
  #pragma unroll 2
  for (int k = k0 + q; k < k1; k += 8){
    int s = colA[k];
    float w = dinv[s];
    const u16* pr = in + (size_t)s*CC + cl*16;
    uint4 u = *(const uint4*)pr;
    uint4 v = *(const uint4*)(pr + 8);
    a[0] = fmaf(w, blo(u.x), a[0]);  a[1] = fmaf(w, bhi(u.x), a[1]);
    a[2] = fmaf(w, blo(u.y), a[2]);  a[3] = fmaf(w, bhi(u.y), a[3]);
    a[4] = fmaf(w, blo(u.z), a[4]);  a[5] = fmaf(w, bhi(u.z), a[5]);
    a[6] = fmaf(w, blo(u.w), a[6]);  a[7] = fmaf(w, bhi(u.w), a[7]);
    a[8] = fmaf(w, blo(v.x), a[8]);  a[9] = fmaf(w, bhi(v.x), a[9]);
    a[10]= fmaf(w, blo(v.y), a[10]); a[11]= fmaf(w, bhi(v.y), a[11]);
    a[12]= fmaf(w, blo(v.z), a[12]); a[13]= fmaf(w, bhi(v.z), a[13]);
    a[14]= fmaf(w, blo(v.w), a[14]); a[15]= fmaf(w, bhi(v.w), a[15]);
  }
  #pragma unroll
  for (int m = 8; m <= 32; m <<= 1){
    #pragma unroll
    for (int i=0;i<16;++i) a[i] += __shfl_xor(a[i], m);
  }
  if (q == 0){
    float wrow = -dinv[row];
    uint4 r0, r1;
    r0.x = (u32)f2bf(wrow*a[0])  | ((u32)f2bf(wrow*a[1])<<16);
    r0.y = (u32)f2bf(wrow*a[2])  | ((u32)f2bf(wrow*a[3])<<16);
    r0.z = (u32)f2bf(wrow*a[4])  | ((u32)f2bf(wrow*a[5])<<16);
    r0.w = (u32)f2bf(wrow*a[6])  | ((u32)f2bf(wrow*a[7])<<16);
    r1.x = (u32)f2bf(wrow*a[8])  | ((u32)f2bf(wrow*a[9])<<16);
    r1.y = (u32)f2bf(wrow*a[10]) | ((u32)f2bf(wrow*a[11])<<16);
    r1.z = (u32)f2bf(wrow*a[12]) | ((u32)f2bf(wrow*a[13])<<16);
    r1.w = (u32)f2bf(wrow*a[14]) | ((u32)f2bf(wrow*a[15])<<16);
    u16* po = out + (size_t)row*CC + cl*16;
    *(uint4*)po = r0;
    *(uint4*)(po + 8) = r1;
  }
}

// single-input (hr path)
__global__ __launch_bounds__(256) void spmm_kernel(const int* __restrict__ rowptr, const u16* __restrict__ colA,
                                                   const float* __restrict__ dinv,
                                                   const u16* __restrict__ in, u16* __restrict__ out){
  int wave = threadIdx.x >> 6, lane = threadIdx.x & 63;
  int wb = blockIdx.x;
  if (wb >= NN/4) return;
  spmm_row4(rowptr, colA, dinv, in, out, wb, wave, lane);
}

// dual-input, XCD-pinned: xcd 0-3 -> input0, 4-7 -> input1; per-XCD L2
// working set = one 2.5MB matrix.
__global__ __launch_bounds__(256) void spmm2_kernel(const int* __restrict__ rowptr, const u16* __restrict__ colA,
                                                    const float* __restrict__ dinv,
                                                    const u16* __restrict__ in0, u16* __restrict__ out0,
                                                    const u16* __restrict__ in1, u16* __restrict__ out1){
  int wave = threadIdx.x >> 6, lane = threadIdx.x & 63;
  int bid = blockIdx.x;
  int xcd = bid & 7;
  int inp = xcd >> 2;
  int wb  = (bid >> 3)*4 + (xcd & 3);
  if (wb >= NN/4) return;
  spmm_row4(rowptr, colA, dinv, inp?in1:in0, inp?out1:out0, wb, wave, lane);
}

// ---------------- bf16 MFMA GEMM over segmented K, BK=128 ------------------
// BM=BN=64, BK=128 (one segment per staging round); 4 waves/block, each a
// 32x32 quadrant. LDS [64 rows][16 x 16B chunks], XOR swizzle chunk^=(row&15),
// staged by global_load_lds with pre-swizzled SOURCE (both-sides rule #21).
// SWZN>0: 1D grid 8*20*SWZN, XCD bid&7 owns a contiguous 20-m-tile stripe.
// EPI 1 + n0>=256 (h~ cols): h-side B rows structurally zero -> K-skip.
template<int NSEG, int KDIM, int EPI, int SWZN>
__global__ __launch_bounds__(256) void mgemm_kernel(
    const u16* __restrict__ A0, const u16* __restrict__ A1, const u16* __restrict__ A2,
    const u16* __restrict__ A3, const u16* __restrict__ A4, const u16* __restrict__ A5,
    const u16* __restrict__ Bt,
    const float* __restrict__ bias0, const float* __restrict__ bias1,
    const u16* __restrict__ hbuf,
    float* __restrict__ zbuf, float* __restrict__ chx,
    u16* __restrict__ hr_out, u16* __restrict__ h_out,
    float* __restrict__ out_f)
{
  __shared__ __align__(16) u16 As[64*128];
  __shared__ __align__(16) u16 Bs[64*128];
  const u16* segs[6] = {A0,A1,A2,A3,A4,A5};
  int tid = threadIdx.x, lane = tid & 63, wvi = tid >> 6;
  int m0, n0;
  if (SWZN > 0){
    int bid = blockIdx.x;
    int j = bid >> 3;
    int mt = (bid & 7)*20 + (j % 20);
    if (mt >= 157) return;
    m0 = mt*64; n0 = (j/20)*64;
  } else {
    m0 = blockIdx.x*64; n0 = blockIdx.y*64;
  }
  int wr = wvi >> 1, wc = wvi & 1;

  f32x4 acc[2][2] = {};

  int c_lo = wvi*64 + lane;
  int rl = lane & 15, rg = lane >> 4;
  int offA[2][4], offB[2][4];
  #pragma unroll
  for (int mf=0; mf<2; ++mf)
    #pragma unroll
    for (int ks=0; ks<4; ++ks){
      offA[mf][ks] = (wr*32 + mf*16 + rl)*256 + ((((ks<<2)+rg) ^ rl)<<4);
      offB[mf][ks] = (wc*32 + mf*16 + rl)*256 + ((((ks<<2)+rg) ^ rl)<<4);
    }

  const int ktend = (EPI==1 && n0 >= 256) ? (NSEG/2) : NSEG;  // K-skip h~ cols
  for (int kt=0; kt<ktend; ++kt){
    const u16* __restrict__ Aseg = segs[kt];
    __syncthreads();
    #pragma unroll
    for (int i=0;i<4;++i){
      int c = i*256 + c_lo;
      int row = c >> 4, slot = c & 15;
      int scw = slot ^ (row & 15);
      int grow = m0 + row; if (grow > NN-1) grow = NN-1;
      gload16(Aseg + (size_t)grow*CC + scw*8,
              (u16*)As + ((size_t)i*256 + wvi*64)*8);
      gload16(Bt + (size_t)(n0 + row)*KDIM + kt*128 + scw*8,
              (u16*)Bs + ((size_t)i*256 + wvi*64)*8);
    }
    __syncthreads();
    #pragma unroll
    for (int ks=0; ks<4; ++ks){
      bf16x8 a0 = *(const bf16x8*)((const char*)As + offA[0][ks]);
      bf16x8 a1 = *(const bf16x8*)((const char*)As + offA[1][ks]);
      bf16x8 b0 = *(const bf16x8*)((const char*)Bs + offB[0][ks]);
      bf16x8 b1 = *(const bf16x8*)((const char*)Bs + offB[1][ks]);
      acc[0][0] = __builtin_amdgcn_mfma_f32_16x16x32_bf16(a0, b0, acc[0][0], 0,0,0);
      acc[0][1] = __builtin_amdgcn_mfma_f32_16x16x32_bf16(a0, b1, acc[0][1], 0,0,0);
      acc[1][0] = __builtin_amdgcn_mfma_f32_16x16x32_bf16(a1, b0, acc[1][0], 0,0,0);
      acc[1][1] = __builtin_amdgcn_mfma_f32_16x16x32_bf16(a1, b1, acc[1][1], 0,0,0);
    }
  }

  // epilogue: C/D layout col=lane&15, row=(lane>>4)*4+reg  [guide m89]
  #pragma unroll
  for (int mf=0; mf<2; ++mf){
    #pragma unroll
    for (int nf=0; nf<2; ++nf){
      #pragma unroll
      for (int r=0; r<4; ++r){
        int grow = m0 + wr*32 + mf*16 + rg*4 + r;
        if (grow >= NN) continue;
        int gcol = n0 + wc*32 + nf*16 + rl;
        float v = acc[mf][nf][r];
        if (EPI==0){
          out_f[(size_t)grow*64 + gcol] = v + bias0[gcol];
        } else if (EPI==1){
          int gate = gcol >> 7, c = gcol & 127;
          size_t idx = (size_t)grow*CC + c;
          if (gate==0)      zbuf[idx] = sigmoidf_(v + bias0[c]);
          else if (gate==1){
            float rr = sigmoidf_(v + bias1[c]);
            hr_out[idx] = f2bf(rr * bf2f(hbuf[idx]));
          } else            chx[idx] = v;
        } else {
          size_t idx = (size_t)grow*CC + gcol;
          float pre = v + chx[idx] + bias0[gcol];
          float ht = tanhf_(pre);
          float zz = zbuf[idx];
          float hv = bf2f(hbuf[idx]);
          h_out[idx] = f2bf(fmaf(zz, hv - ht, ht));
        }
      }
    }
  }
}

extern "C" void kernel_launch(void* const* d_in, const int* in_sizes, int n_in,
                              void* d_out, int out_size, void* d_ws, size_t ws_size,
                              hipStream_t stream)
{
  (void)in_sizes; (void)n_in; (void)out_size; (void)ws_size;
  const float* feat = (const float*)d_in[0];
  const int*   edges = (const int*)d_in[1];
  const float* Wxz=(const float*)d_in[2];  const float* bxz=(const float*)d_in[3];
  const float* Whz=(const float*)d_in[4];  const float* bhz=(const float*)d_in[5];
  const float* Wxr=(const float*)d_in[6];  const float* bxr=(const float*)d_in[7];
  const float* Whr=(const float*)d_in[8];  const float* bhr=(const float*)d_in[9];
  const float* Wxh=(const float*)d_in[10]; const float* bxh=(const float*)d_in[11];
  const float* Whh=(const float*)d_in[12]; const float* bhh=(const float*)d_in[13];
  const float* Wp =(const float*)d_in[14]; const float* bp =(const float*)d_in[15];
  float* out = (float*)d_out;

  char* p = (char*)d_ws;
  auto alloc = [&](size_t bytes)->char* {
    char* r = p; p += (bytes + 255) & ~(size_t)255; return r;
  };
  u16* xb   = (u16*)alloc((size_t)T_STEPS*NC*2);
  u16* h    = (u16*)alloc((size_t)NC*2);
  u16* a1x  = (u16*)alloc((size_t)NC*2);
  u16* a2x  = (u16*)alloc((size_t)NC*2);
  u16* a1h  = (u16*)alloc((size_t)NC*2);
  u16* a2h  = (u16*)alloc((size_t)NC*2);
  u16* hr   = (u16*)alloc((size_t)NC*2);
  float* zbuf = (float*)alloc((size_t)NC*4);
  float* chx  = (float*)alloc((size_t)NC*4);
  u16* WbigT = (u16*)alloc(384*768*2);
  u16* WrT   = (u16*)alloc(128*384*2);
  u16* WpT   = (u16*)alloc(64*128*2);
  float* bz  = (float*)alloc(CC*4);
  float* br  = (float*)alloc(CC*4);
  float* bht = (float*)alloc(CC*4);
  float* dinv_all = (float*)alloc((size_t)T_STEPS*NN*4);
  int* rowptr_all = (int*)alloc((size_t)T_STEPS*(NN+1)*4);
  u16* colA_all   = (u16*)alloc((size_t)T_STEPS*EE*2);
  int* chunk_tot  = (int*)alloc((size_t)T_STEPS*NCHK*4);
  int* chunk_base = (int*)alloc((size_t)T_STEPS*NCHK*4);
  // packed hist partials (12.8MB) alias hr+zbuf+chx (contiguous exact-256B
  // sizes; dead before the recurrence loop first writes them)
  u32* histP = (u32*)hr;

  prep_kernel<<<NC/256, 256, 0, stream>>>(Wxz,Whz,Wxr,Whr,Wxh,Whh,
                                          bxz,bhz,bxr,bhr,bxh,bhh, Wp,
                                          WbigT, WrT, WpT, bz, br, bht, h);
  xconv_kernel<<<(T_STEPS*NC/4 + 255)/256, 256, 0, stream>>>(feat, xb, T_STEPS*NC/4);

  hist_kernel<<<dim3(BHIST, T_STEPS), 512, 0, stream>>>(edges, histP);
  reduce_scan_kernel<<<dim3(NCHK, T_STEPS), 256, 0, stream>>>(histP, rowptr_all, chunk_tot, dinv_all);
  scanb_kernel<<<T_STEPS, 64, 0, stream>>>(chunk_tot, chunk_base, rowptr_all);
  scanc_kernel<<<dim3(NCHK, T_STEPS), 256, 0, stream>>>(rowptr_all, chunk_base);
  place_kernel<<<dim3(BHIST, T_STEPS), 512, 0, stream>>>(edges, rowptr_all, histP, colA_all);

  for (int t=0; t<T_STEPS; ++t){
    const int*   rowptr = rowptr_all + (size_t)t*(NN+1);
    const u16*   colA   = colA_all + (size_t)t*EE;
    const float* dinv   = dinv_all + (size_t)t*NN;
    const u16*   x      = xb + (size_t)t*NC;

    spmm2_kernel<<<dim3(2*(NN/4)), 256, 0, stream>>>(rowptr,colA,dinv, x,a1x, h,a1h);
    spmm2_kernel<<<dim3(2*(NN/4)), 256, 0, stream>>>(rowptr,colA,dinv, a1x,a2x, a1h,a2h);

    mgemm_kernel<6,768,1,6><<<dim3(8*20*6), 256, 0, stream>>>(
        x,a1x,a2x,h,a1h,a2h, WbigT, bz, br, h, zbuf, chx, hr, nullptr, nullptr);

    spmm_kernel<<<dim3(NN/4), 256, 0, stream>>>(rowptr,colA,dinv, hr, a1x);
    spmm_kernel<<<dim3(NN/4), 256, 0, stream>>>(rowptr,colA,dinv, a1x, a2x);

    mgemm_kernel<3,384,2,2><<<dim3(8*20*2), 256, 0, stream>>>(
        hr,a1x,a2x,nullptr,nullptr,nullptr, WrT, bht, nullptr, h, zbuf, chx,
        nullptr, h, nullptr);
  }

  mgemm_kernel<1,128,0,0><<<dim3(157,1), 256, 0, stream>>>(
      h,nullptr,nullptr,nullptr,nullptr,nullptr, WpT, bp, nullptr,
      nullptr, nullptr, nullptr, nullptr, nullptr, out);
}

// Round 16
// 872.748 us; speedup vs baseline: 1.0584x; 1.0125x over previous
//
#include <hip/hip_runtime.h>

#define T_STEPS 10
#define NN 10000
#define EE 320000
#define CC 128
#define NC (NN*CC)
#define BHIST 32
#define EPB (EE/BHIST)   // 10000 edges per hist/place block
#define NCHK 40          // ceil(NN/256) scan chunks

typedef unsigned short u16;
typedef unsigned int u32;
typedef __attribute__((ext_vector_type(8))) short bf16x8;
typedef __attribute__((ext_vector_type(4))) float f32x4;

__device__ __forceinline__ float sigmoidf_(float x){ return 1.f/(1.f+__expf(-x)); }
__device__ __forceinline__ float tanhf_(float x){
  x = fminf(15.f, fmaxf(-15.f, x));
  float e = __expf(2.f*x);
  return (e-1.f)/(e+1.f);
}
__device__ __forceinline__ u16 f2bf(float f){
  u32 u = __float_as_uint(f);
  u32 r = u + 0x7fffu + ((u>>16)&1u);
  return (u16)(r>>16);
}
__device__ __forceinline__ float bf2f(u16 s){
  return __uint_as_float(((u32)s)<<16);
}
__device__ __forceinline__ float blo(u32 u){ return __uint_as_float(u<<16); }
__device__ __forceinline__ float bhi(u32 u){ return __uint_as_float(u & 0xffff0000u); }
__device__ __forceinline__ void gload16(const void* g, void* l){
  __builtin_amdgcn_global_load_lds(
    (const __attribute__((address_space(1))) void*)g,
    (__attribute__((address_space(3))) void*)l, 16, 0, 0);
}

// ---------------- prep: transposed bf16 effective weights + biases + h0 -----
__global__ __launch_bounds__(256) void prep_kernel(
    const float* __restrict__ Wxz, const float* __restrict__ Whz,
    const float* __restrict__ Wxr, const float* __restrict__ Whr,
    const float* __restrict__ Wxh, const float* __restrict__ Whh,
    const float* __restrict__ bxz, const float* __restrict__ bhz,
    const float* __restrict__ bxr, const float* __restrict__ bhr,
    const float* __restrict__ bxh, const float* __restrict__ bhh,
    const float* __restrict__ Wp,
    u16* __restrict__ WbigT, u16* __restrict__ WrT, u16* __restrict__ WpT,
    float* __restrict__ bz, float* __restrict__ br, float* __restrict__ bht,
    u16* __restrict__ h)
{
  int idx = blockIdx.x*256 + threadIdx.x;
  if (idx < NC) h[idx] = 0;
  if (idx < 384*768) {
    int c = idx / 768, k = idx - c*768;
    int gate = c >> 7, cc = c & 127;
    int hside = (k >= 384);
    int kk = hside ? k - 384 : k;
    int blk = kk >> 7, row = kk & 127;
    const float* W = nullptr;
    if (!hside) W = (gate==0) ? Wxz : (gate==1) ? Wxr : Wxh;
    else if (gate==0) W = Whz; else if (gate==1) W = Whr;
    float v = 0.f;
    if (W) {
      int base = row*CC + cc;
      float w0 = W[base], w1 = W[CC*CC + base], w2 = W[2*CC*CC + base];
      v = (blk==0) ? (w0 - w2) : (blk==1) ? w1 : (2.f*w2);
    }
    WbigT[idx] = f2bf(v);
  }
  if (idx < 128*384) {
    int c = idx / 384, k = idx - c*384;
    int blk = k >> 7, row = k & 127;
    int base = row*CC + c;
    float w0 = Whh[base], w1 = Whh[CC*CC+base], w2 = Whh[2*CC*CC+base];
    WrT[idx] = f2bf((blk==0) ? (w0-w2) : (blk==1) ? w1 : (2.f*w2));
  }
  if (idx < 64*128) {
    int c = idx >> 7, k = idx & 127;
    WpT[idx] = f2bf(Wp[k*64 + c]);
  }
  if (idx < CC) {
    bz[idx]  = bxz[idx] + bhz[idx];
    br[idx]  = bxr[idx] + bhr[idx];
    bht[idx] = bxh[idx] + bhh[idx];
  }
}

// fp32 -> bf16, 4 elems/thread; n4 = number of float4 chunks
__global__ __launch_bounds__(256) void xconv_kernel(const float* __restrict__ x, u16* __restrict__ xb, int n4){
  int i = blockIdx.x*256 + threadIdx.x;
  if (i >= n4) return;
  long long o = (long long)i*4;
  float4 v = *(const float4*)(x + o);
  u32 u0 = (u32)f2bf(v.x) | ((u32)f2bf(v.y)<<16);
  u32 u1 = (u32)f2bf(v.z) | ((u32)f2bf(v.w)<<16);
  uint2 r; r.x=u0; r.y=u1;
  *(uint2*)(xb + o) = r;
}

// ---------------- graph build: packed LDS histograms, zero global atomics --
__global__ __launch_bounds__(512) void hist_kernel(const int* __restrict__ edges,
                                                   u32* __restrict__ histP){
  __shared__ u32 hist[NN];   // 40 KB
  int t = blockIdx.y, b = blockIdx.x, tid = threadIdx.x;
  for (int i = tid; i < NN; i += 512) hist[i] = 0;
  __syncthreads();
  const int* src = edges + (size_t)t*2*EE;
  const int* dst = src + EE;
  int e1 = b*EPB + EPB;
  #pragma unroll 4
  for (int e = b*EPB + tid; e < e1; e += 512){
    int s = src[e], d = dst[e];
    if (s != d){
      atomicAdd(&hist[s], 1u);         // ds_add, LDS-local
      atomicAdd(&hist[d], 1u << 16);
    }
  }
  __syncthreads();
  u32* hp = histP + ((size_t)t*BHIST + b)*NN;
  for (int i = tid; i < NN; i += 512) hp[i] = hist[i];
}

// reduce+chunk-scan: per (t,chunk of 256 nodes): deg->dinv; per-block cnt
// exclusive prefix into partial high16; chunk-local exclusive scan into
// rowptr; chunk totals out.
__global__ __launch_bounds__(256) void reduce_scan_kernel(u32* __restrict__ histP,
                                                          int* __restrict__ rowptr_all,
                                                          int* __restrict__ chunk_tot,
                                                          float* __restrict__ dinv_all){
  int t = blockIdx.y, ch = blockIdx.x, tid = threadIdx.x;
  int d = ch*256 + tid;
  u32 run=0, degs=0;
  if (d < NN){
    size_t base = (size_t)t*BHIST*NN + d;
    #pragma unroll
    for (int b=0;b<BHIST;++b){
      size_t ix = base + (size_t)b*NN;
      u32 v = histP[ix];
      histP[ix] = (v & 0xffffu) | (run<<16);
      run += v>>16;
      degs += v & 0xffffu;
    }
    dinv_all[t*NN+d] = degs>0 ? rsqrtf((float)degs) : 0.f;
  }
  int lane = tid&63, wv = tid>>6;
  int s = (int)run;
  #pragma unroll
  for (int off=1; off<64; off<<=1){
    int u = __shfl_up(s, off, 64);
    if (lane>=off) s += u;
  }
  __shared__ int wsum[4];
  if (lane==63) wsum[wv] = s;
  __syncthreads();
  int add = 0;
  #pragma unroll
  for (int w=0; w<3; ++w) if (w < wv) add += wsum[w];
  int incl = s + add;
  if (d < NN) rowptr_all[(size_t)t*(NN+1)+d] = incl - (int)run;
  if (tid==255) chunk_tot[t*NCHK + ch] = incl;
}

// scan of NCHK chunk totals per t (one wave)
__global__ __launch_bounds__(64) void scanb_kernel(const int* __restrict__ chunk_tot,
                                                   int* __restrict__ chunk_base,
                                                   int* __restrict__ rowptr_all){
  int t = blockIdx.x; int lane = threadIdx.x;
  int v = (lane < NCHK) ? chunk_tot[t*NCHK+lane] : 0;
  int s = v;
  #pragma unroll
  for (int off=1; off<64; off<<=1){
    int u = __shfl_up(s, off, 64);
    if (lane>=off) s += u;
  }
  if (lane < NCHK) chunk_base[t*NCHK+lane] = s - v;
  if (lane == NCHK-1) rowptr_all[(size_t)t*(NN+1)+NN] = s;
}

__global__ __launch_bounds__(256) void scanc_kernel(int* __restrict__ rowptr_all,
                                                    const int* __restrict__ chunk_base){
  int t = blockIdx.y, ch = blockIdx.x;
  int d = ch*256 + threadIdx.x;
  if (d < NN) rowptr_all[(size_t)t*(NN+1)+d] += chunk_base[t*NCHK+ch];
}

// place (r12 version, proven ~50us): counting-sort scatter. LDS counters
// seeded with rowptr + per-block exclusive base; rank via LDS atomics.
__global__ __launch_bounds__(512) void place_kernel(const int* __restrict__ edges,
                                                    const int* __restrict__ rowptr_all,
                                                    const u32* __restrict__ histP,
                                                    u16* __restrict__ colA_all){
  __shared__ int slot[NN];     // 40 KB
  int t = blockIdx.y, b = blockIdx.x, tid = threadIdx.x;
  const int* rowptr = rowptr_all + (size_t)t*(NN+1);
  const u32* hp = histP + ((size_t)t*BHIST + b)*NN;
  for (int i = tid; i < NN; i += 512) slot[i] = rowptr[i] + (int)(hp[i] >> 16);
  __syncthreads();
  const int* src = edges + (size_t)t*2*EE;
  const int* dst = src + EE;
  u16* colA = colA_all + (size_t)t*EE;
  int e1 = b*EPB + EPB;
  #pragma unroll 4
  for (int e = b*EPB + tid; e < e1; e += 512){
    int s = src[e], d = dst[e];
    if (s != d){
      int pos = atomicAdd(&slot[d], 1);   // LDS atomic, returns rank
      colA[pos] = (u16)s;
    }
  }
}

// ---------------- CSR SpMM core: quad-edge, one wave per row ---------------
// (r12 version — the proven-best MLP depth; oct was neutral-to-worse.)
// 4 lane-groups of 16; group q processes edges k0+q, k0+q+4, ...; each group
// covers all 128 channels via uint4 -> 4 edges in flight, trips/4.
// Merge via shfl_xor(16)+shfl_xor(32); group 0 writes 16B.
__device__ __forceinline__ void spmm_row4(const int* __restrict__ rowptr, const u16* __restrict__ colA,
                                          const float* __restrict__ dinv,
                                          const u16* __restrict__ in, u16* __restrict__ out,
                                          int wb, int wave, int lane){
  int row = wb*4 + wave;
  int k0 = rowptr[row], k1 = rowptr[row+1];
  int q = lane >> 4, cl = lane & 15;      // channels 8cl..8cl+7
  float a0=0.f,a1=0.f,a2=0.f,a3=0.f,a4=0.f,a5=0.f,a6=0.f,a7=0.f;
  #pragma unroll 2
  for (int k = k0 + q; k < k1; k += 4){
    int s = colA[k];
    float w = dinv[s];
    uint4 u = *(const uint4*)(in + (size_t)s*CC + cl*8);
    a0 = fmaf(w, blo(u.x), a0);  a1 = fmaf(w, bhi(u.x), a1);
    a2 = fmaf(w, blo(u.y), a2);  a3 = fmaf(w, bhi(u.y), a3);
    a4 = fmaf(w, blo(u.z), a4);  a5 = fmaf(w, bhi(u.z), a5);
    a6 = fmaf(w, blo(u.w), a6);  a7 = fmaf(w, bhi(u.w), a7);
  }
  a0 += __shfl_xor(a0,16); a1 += __shfl_xor(a1,16);
  a2 += __shfl_xor(a2,16); a3 += __shfl_xor(a3,16);
  a4 += __shfl_xor(a4,16); a5 += __shfl_xor(a5,16);
  a6 += __shfl_xor(a6,16); a7 += __shfl_xor(a7,16);
  a0 += __shfl_xor(a0,32); a1 += __shfl_xor(a1,32);
  a2 += __shfl_xor(a2,32); a3 += __shfl_xor(a3,32);
  a4 += __shfl_xor(a4,32); a5 += __shfl_xor(a5,32);
  a6 += __shfl_xor(a6,32); a7 += __shfl_xor(a7,32);
  if (q == 0){
    float wrow = -dinv[row];
    uint4 r;
    r.x = (u32)f2bf(wrow*a0) | ((u32)f2bf(wrow*a1)<<16);
    r.y = (u32)f2bf(wrow*a2) | ((u32)f2bf(wrow*a3)<<16);
    r.z = (u32)f2bf(wrow*a4) | ((u32)f2bf(wrow*a5)<<16);
    r.w = (u32)f2bf(wrow*a6) | ((u32)f2bf(wrow*a7)<<16);
    *(uint4*)(out + (size_t)row*CC + cl*8) = r;
  }
}

// single-input (hr path)
__global__ __launch_bounds__(256) void spmm_kernel(const int* __restrict__ rowptr, const u16* __restrict__ colA,
                                                   const float* __restrict__ dinv,
                                                   const u16* __restrict__ in, u16* __restrict__ out){
  int wave = threadIdx.x >> 6, lane = threadIdx.x & 63;
  int wb = blockIdx.x;
  if (wb >= NN/4) return;
  spmm_row4(rowptr, colA, dinv, in, out, wb, wave, lane);
}

// dual-input, XCD-pinned: xcd 0-3 -> input0, 4-7 -> input1; per-XCD L2
// working set = one 2.5MB matrix.
__global__ __launch_bounds__(256) void spmm2_kernel(const int* __restrict__ rowptr, const u16* __restrict__ colA,
                                                    const float* __restrict__ dinv,
                                                    const u16* __restrict__ in0, u16* __restrict__ out0,
                                                    const u16* __restrict__ in1, u16* __restrict__ out1){
  int wave = threadIdx.x >> 6, lane = threadIdx.x & 63;
  int bid = blockIdx.x;
  int xcd = bid & 7;
  int inp = xcd >> 2;
  int wb  = (bid >> 3)*4 + (xcd & 3);
  if (wb >= NN/4) return;
  spmm_row4(rowptr, colA, dinv, inp?in1:in0, inp?out1:out0, wb, wave, lane);
}

// ---------------- bf16 MFMA GEMM over segmented K, BK=128 ------------------
// BM=BN=64, BK=128 (one segment per staging round; r13 decomposition showed
// ~-6us vs BK=64 at unchanged grid/occupancy); 4 waves/block, each a 32x32
// quadrant. LDS [64 rows][16 x 16B chunks], XOR swizzle chunk^=(row&15),
// staged by global_load_lds with pre-swizzled SOURCE (both-sides rule #21).
// SWZN>0: 1D grid 8*20*SWZN, XCD bid&7 owns a contiguous 20-m-tile stripe.
// EPI 1 + n0>=256 (h~ cols): h-side B rows structurally zero -> K-skip.
template<int NSEG, int KDIM, int EPI, int SWZN>
__global__ __launch_bounds__(256) void mgemm_kernel(
    const u16* __restrict__ A0, const u16* __restrict__ A1, const u16* __restrict__ A2,
    const u16* __restrict__ A3, const u16* __restrict__ A4, const u16* __restrict__ A5,
    const u16* __restrict__ Bt,
    const float* __restrict__ bias0, const float* __restrict__ bias1,
    const u16* __restrict__ hbuf,
    float* __restrict__ zbuf, float* __restrict__ chx,
    u16* __restrict__ hr_out, u16* __restrict__ h_out,
    float* __restrict__ out_f)
{
  __shared__ __align__(16) u16 As[64*128];
  __shared__ __align__(16) u16 Bs[64*128];
  const u16* segs[6] = {A0,A1,A2,A3,A4,A5};
  int tid = threadIdx.x, lane = tid & 63, wvi = tid >> 6;
  int m0, n0;
  if (SWZN > 0){
    int bid = blockIdx.x;
    int j = bid >> 3;
    int mt = (bid & 7)*20 + (j % 20);
    if (mt >= 157) return;
    m0 = mt*64; n0 = (j/20)*64;
  } else {
    m0 = blockIdx.x*64; n0 = blockIdx.y*64;
  }
  int wr = wvi >> 1, wc = wvi & 1;

  f32x4 acc[2][2] = {};

  int c_lo = wvi*64 + lane;
  int rl = lane & 15, rg = lane >> 4;
  int offA[2][4], offB[2][4];
  #pragma unroll
  for (int mf=0; mf<2; ++mf)
    #pragma unroll
    for (int ks=0; ks<4; ++ks){
      offA[mf][ks] = (wr*32 + mf*16 + rl)*256 + ((((ks<<2)+rg) ^ rl)<<4);
      offB[mf][ks] = (wc*32 + mf*16 + rl)*256 + ((((ks<<2)+rg) ^ rl)<<4);
    }

  const int ktend = (EPI==1 && n0 >= 256) ? (NSEG/2) : NSEG;  // K-skip h~ cols
  for (int kt=0; kt<ktend; ++kt){
    const u16* __restrict__ Aseg = segs[kt];
    __syncthreads();
    #pragma unroll
    for (int i=0;i<4;++i){
      int c = i*256 + c_lo;
      int row = c >> 4, slot = c & 15;
      int scw = slot ^ (row & 15);
      int grow = m0 + row; if (grow > NN-1) grow = NN-1;
      gload16(Aseg + (size_t)grow*CC + scw*8,
              (u16*)As + ((size_t)i*256 + wvi*64)*8);
      gload16(Bt + (size_t)(n0 + row)*KDIM + kt*128 + scw*8,
              (u16*)Bs + ((size_t)i*256 + wvi*64)*8);
    }
    __syncthreads();
    #pragma unroll
    for (int ks=0; ks<4; ++ks){
      bf16x8 a0 = *(const bf16x8*)((const char*)As + offA[0][ks]);
      bf16x8 a1 = *(const bf16x8*)((const char*)As + offA[1][ks]);
      bf16x8 b0 = *(const bf16x8*)((const char*)Bs + offB[0][ks]);
      bf16x8 b1 = *(const bf16x8*)((const char*)Bs + offB[1][ks]);
      acc[0][0] = __builtin_amdgcn_mfma_f32_16x16x32_bf16(a0, b0, acc[0][0], 0,0,0);
      acc[0][1] = __builtin_amdgcn_mfma_f32_16x16x32_bf16(a0, b1, acc[0][1], 0,0,0);
      acc[1][0] = __builtin_amdgcn_mfma_f32_16x16x32_bf16(a1, b0, acc[1][0], 0,0,0);
      acc[1][1] = __builtin_amdgcn_mfma_f32_16x16x32_bf16(a1, b1, acc[1][1], 0,0,0);
    }
  }

  // epilogue: C/D layout col=lane&15, row=(lane>>4)*4+reg  [guide m89]
  #pragma unroll
  for (int mf=0; mf<2; ++mf){
    #pragma unroll
    for (int nf=0; nf<2; ++nf){
      #pragma unroll
      for (int r=0; r<4; ++r){
        int grow = m0 + wr*32 + mf*16 + rg*4 + r;
        if (grow >= NN) continue;
        int gcol = n0 + wc*32 + nf*16 + rl;
        float v = acc[mf][nf][r];
        if (EPI==0){
          out_f[(size_t)grow*64 + gcol] = v + bias0[gcol];
        } else if (EPI==1){
          int gate = gcol >> 7, c = gcol & 127;
          size_t idx = (size_t)grow*CC + c;
          if (gate==0)      zbuf[idx] = sigmoidf_(v + bias0[c]);
          else if (gate==1){
            float rr = sigmoidf_(v + bias1[c]);
            hr_out[idx] = f2bf(rr * bf2f(hbuf[idx]));
          } else            chx[idx] = v;
        } else {
          size_t idx = (size_t)grow*CC + gcol;
          float pre = v + chx[idx] + bias0[gcol];
          float ht = tanhf_(pre);
          float zz = zbuf[idx];
          float hv = bf2f(hbuf[idx]);
          h_out[idx] = f2bf(fmaf(zz, hv - ht, ht));
        }
      }
    }
  }
}

extern "C" void kernel_launch(void* const* d_in, const int* in_sizes, int n_in,
                              void* d_out, int out_size, void* d_ws, size_t ws_size,
                              hipStream_t stream)
{
  (void)in_sizes; (void)n_in; (void)out_size; (void)ws_size;
  const float* feat = (const float*)d_in[0];
  const int*   edges = (const int*)d_in[1];
  const float* Wxz=(const float*)d_in[2];  const float* bxz=(const float*)d_in[3];
  const float* Whz=(const float*)d_in[4];  const float* bhz=(const float*)d_in[5];
  const float* Wxr=(const float*)d_in[6];  const float* bxr=(const float*)d_in[7];
  const float* Whr=(const float*)d_in[8];  const float* bhr=(const float*)d_in[9];
  const float* Wxh=(const float*)d_in[10]; const float* bxh=(const float*)d_in[11];
  const float* Whh=(const float*)d_in[12]; const float* bhh=(const float*)d_in[13];
  const float* Wp =(const float*)d_in[14]; const float* bp =(const float*)d_in[15];
  float* out = (float*)d_out;

  char* p = (char*)d_ws;
  auto alloc = [&](size_t bytes)->char* {
    char* r = p; p += (bytes + 255) & ~(size_t)255; return r;
  };
  u16* xb   = (u16*)alloc((size_t)T_STEPS*NC*2);
  u16* h    = (u16*)alloc((size_t)NC*2);
  u16* a1x  = (u16*)alloc((size_t)NC*2);
  u16* a2x  = (u16*)alloc((size_t)NC*2);
  u16* a1h  = (u16*)alloc((size_t)NC*2);
  u16* a2h  = (u16*)alloc((size_t)NC*2);
  u16* hr   = (u16*)alloc((size_t)NC*2);
  float* zbuf = (float*)alloc((size_t)NC*4);
  float* chx  = (float*)alloc((size_t)NC*4);
  u16* WbigT = (u16*)alloc(384*768*2);
  u16* WrT   = (u16*)alloc(128*384*2);
  u16* WpT   = (u16*)alloc(64*128*2);
  float* bz  = (float*)alloc(CC*4);
  float* br  = (float*)alloc(CC*4);
  float* bht = (float*)alloc(CC*4);
  float* dinv_all = (float*)alloc((size_t)T_STEPS*NN*4);
  int* rowptr_all = (int*)alloc((size_t)T_STEPS*(NN+1)*4);
  u16* colA_all   = (u16*)alloc((size_t)T_STEPS*EE*2);
  int* chunk_tot  = (int*)alloc((size_t)T_STEPS*NCHK*4);
  int* chunk_base = (int*)alloc((size_t)T_STEPS*NCHK*4);
  // packed hist partials (12.8MB) alias hr+zbuf+chx (contiguous exact-256B
  // sizes; dead before the recurrence loop first writes them)
  u32* histP = (u32*)hr;

  prep_kernel<<<NC/256, 256, 0, stream>>>(Wxz,Whz,Wxr,Whr,Wxh,Whh,
                                          bxz,bhz,bxr,bhr,bxh,bhh, Wp,
                                          WbigT, WrT, WpT, bz, br, bht, h);
  xconv_kernel<<<(T_STEPS*NC/4 + 255)/256, 256, 0, stream>>>(feat, xb, T_STEPS*NC/4);

  hist_kernel<<<dim3(BHIST, T_STEPS), 512, 0, stream>>>(edges, histP);
  reduce_scan_kernel<<<dim3(NCHK, T_STEPS), 256, 0, stream>>>(histP, rowptr_all, chunk_tot, dinv_all);
  scanb_kernel<<<T_STEPS, 64, 0, stream>>>(chunk_tot, chunk_base, rowptr_all);
  scanc_kernel<<<dim3(NCHK, T_STEPS), 256, 0, stream>>>(rowptr_all, chunk_base);
  place_kernel<<<dim3(BHIST, T_STEPS), 512, 0, stream>>>(edges, rowptr_all, histP, colA_all);

  for (int t=0; t<T_STEPS; ++t){
    const int*   rowptr = rowptr_all + (size_t)t*(NN+1);
    const u16*   colA   = colA_all + (size_t)t*EE;
    const float* dinv   = dinv_all + (size_t)t*NN;
    const u16*   x      = xb + (size_t)t*NC;

    spmm2_kernel<<<dim3(2*(NN/4)), 256, 0, stream>>>(rowptr,colA,dinv, x,a1x, h,a1h);
    spmm2_kernel<<<dim3(2*(NN/4)), 256, 0, stream>>>(rowptr,colA,dinv, a1x,a2x, a1h,a2h);

    mgemm_kernel<6,768,1,6><<<dim3(8*20*6), 256, 0, stream>>>(
        x,a1x,a2x,h,a1h,a2h, WbigT, bz, br, h, zbuf, chx, hr, nullptr, nullptr);

    spmm_kernel<<<dim3(NN/4), 256, 0, stream>>>(rowptr,colA,dinv, hr, a1x);
    spmm_kernel<<<dim3(NN/4), 256, 0, stream>>>(rowptr,colA,dinv, a1x, a2x);

    mgemm_kernel<3,384,2,2><<<dim3(8*20*2), 256, 0, stream>>>(
        hr,a1x,a2x,nullptr,nullptr,nullptr, WrT, bht, nullptr, h, zbuf, chx,
        nullptr, h, nullptr);
  }

  mgemm_kernel<1,128,0,0><<<dim3(157,1), 256, 0, stream>>>(
      h,nullptr,nullptr,nullptr,nullptr,nullptr, WpT, bp, nullptr,
      nullptr, nullptr, nullptr, nullptr, nullptr, out);
}